// Round 14
// baseline (366.348 us; speedup 1.0000x reference)
//
#include <hip/hip_runtime.h>
#include <stdint.h>

#define BATCH 8192
#define NJOB  1179648   // 8192*144

// ---------------------------------------------------------------------------
// Stage 0 (merged): pack binarized weights + alphas + per-block zero flags.
// ---------------------------------------------------------------------------
__global__ __launch_bounds__(256) void k_pack(const float* __restrict__ w2,
    const float* __restrict__ w3, unsigned* __restrict__ wpos2,
    unsigned* __restrict__ wneg2, float* __restrict__ alpha2,
    unsigned* __restrict__ wpos3, unsigned* __restrict__ wneg3,
    float* __restrict__ alpha3, int* __restrict__ flags2, int* __restrict__ flags3){
  __shared__ int zf;
  int tid = threadIdx.x;
  if (tid == 0) zf = 0;
  __syncthreads();
  if (blockIdx.x < 5){
    int t = blockIdx.x*256 + tid;
    int had0 = 0;
    if (t < 1250){                     // t = o*25 + k
      int o = t/25, k = t%25;
      unsigned p=0, n=0;
      for (int i=0;i<20;i++){
        float v = w2[(o*20+i)*25 + k];
        if (v > 0.f) p |= 1u<<i;
        else if (v < 0.f) n |= 1u<<i;
        else had0 = 1;
      }
      wpos2[t] = p; wneg2[t] = n;
    }
    if (t < 50){
      float s = 0.f;
      for (int i=0;i<500;i++) s += fabsf(w2[t*500+i]);
      alpha2[t] = s / 500.f;
    }
    if (had0) atomicOr(&zf, 1);
    __syncthreads();
    if (tid == 0) flags2[blockIdx.x] = zf;
  } else {
    int t = (blockIdx.x-5)*256 + tid;
    int had0 = 0;
    if (t < 12500){                    // t = j*25 + w
      int j = t/25, w = t%25;
      unsigned p=0, n=0;
      for (int bb=0;bb<32;bb++){
        float v = w3[j*800 + w*32 + bb];
        if (v > 0.f) p |= 1u<<bb;
        else if (v < 0.f) n |= 1u<<bb;
        else had0 = 1;
      }
      wpos3[t] = p; wneg3[t] = n;
    }
    if (t < 500){
      float s = 0.f;
      for (int i=0;i<800;i++) s += fabsf(w3[t*800+i]);
      alpha3[t] = s / 800.f;
    }
    if (had0) atomicOr(&zf, 1);
    __syncthreads();
    if (tid == 0) flags3[blockIdx.x-5] = zf;
  }
}

// ---------------------------------------------------------------------------
// Stage 1: conv1 (fp32). 8 images/block, grid 1024. Channel-pair outer loop.
// Patch PRELOADED as 18 float2 upfront (one lgkmcnt group), then pure FMA
// burst — removes the per-row load/wait bubble (r12 showed VALUBusy 62%
// invariant to occupancy => issue-bubble, not wave starvation).
// ---------------------------------------------------------------------------

// element (row r, col c) of the 6x6 patch held in a2[18] (float2 pairs)
#define PE(r,c) (((c)&1) ? a2[(r)*3+((c)>>1)].y : a2[(r)*3+((c)>>1)].x)

#define CONV1_PATCH_FMA(IPTR)                                                 \
  float2 a2[18];                                                              \
  {                                                                           \
    const float2* rp0 = (const float2*)((IPTR));                              \
    const float2* rp1 = (const float2*)((IPTR) + 28);                         \
    const float2* rp2 = (const float2*)((IPTR) + 56);                         \
    const float2* rp3 = (const float2*)((IPTR) + 84);                         \
    const float2* rp4 = (const float2*)((IPTR) + 112);                        \
    const float2* rp5 = (const float2*)((IPTR) + 140);                        \
    a2[0]=rp0[0];  a2[1]=rp0[1];  a2[2]=rp0[2];                               \
    a2[3]=rp1[0];  a2[4]=rp1[1];  a2[5]=rp1[2];                               \
    a2[6]=rp2[0];  a2[7]=rp2[1];  a2[8]=rp2[2];                               \
    a2[9]=rp3[0];  a2[10]=rp3[1]; a2[11]=rp3[2];                              \
    a2[12]=rp4[0]; a2[13]=rp4[1]; a2[14]=rp4[2];                              \
    a2[15]=rp5[0]; a2[16]=rp5[1]; a2[17]=rp5[2];                              \
  }                                                                           \
  float vA0=0.f,vA1=0.f,vA2=0.f,vA3=0.f;                                      \
  float vB0=0.f,vB1=0.f,vB2=0.f,vB3=0.f;                                      \
  _Pragma("unroll")                                                           \
  for (int ky=0;ky<5;ky++)                                                    \
    _Pragma("unroll")                                                         \
    for (int kx=0;kx<5;kx++){                                                 \
      float w = wa[ky*5+kx], u = wb[ky*5+kx];                                 \
      float e00=PE(ky,kx), e01=PE(ky,kx+1);                                   \
      float e10=PE(ky+1,kx), e11=PE(ky+1,kx+1);                               \
      vA0=fmaf(e00,w,vA0); vA1=fmaf(e01,w,vA1);                               \
      vA2=fmaf(e10,w,vA2); vA3=fmaf(e11,w,vA3);                               \
      vB0=fmaf(e00,u,vB0); vB1=fmaf(e01,u,vB1);                               \
      vB2=fmaf(e10,u,vB2); vB3=fmaf(e11,u,vB3);                               \
    }

// legacy row-streaming form (used by the recompute fallback k_conv1_bin)
#define CONV1_ROWS(IPTR)                                                      \
  float vA0=0.f,vA1=0.f,vA2=0.f,vA3=0.f;                                      \
  float vB0=0.f,vB1=0.f,vB2=0.f,vB3=0.f;                                      \
  _Pragma("unroll")                                                           \
  for (int r=0;r<6;r++){                                                      \
    const float2* rp = (const float2*)((IPTR) + r*28);                        \
    float2 p0 = rp[0], p1 = rp[1], p2 = rp[2];                                \
    float row0=p0.x, row1=p0.y, row2=p1.x, row3=p1.y, row4=p2.x, row5=p2.y;   \
    if (r<5){                                                                 \
      _Pragma("unroll")                                                       \
      for (int kx=0;kx<5;kx++){                                               \
        float e0 = (kx==0?row0:kx==1?row1:kx==2?row2:kx==3?row3:row4);        \
        float e1 = (kx==0?row1:kx==1?row2:kx==2?row3:kx==3?row4:row5);        \
        float w = wa[r*5+kx], u = wb[r*5+kx];                                 \
        vA0=fmaf(e0,w,vA0); vA1=fmaf(e1,w,vA1);                               \
        vB0=fmaf(e0,u,vB0); vB1=fmaf(e1,u,vB1);                               \
      }                                                                       \
    }                                                                         \
    if (r>0){                                                                 \
      _Pragma("unroll")                                                       \
      for (int kx=0;kx<5;kx++){                                               \
        float e0 = (kx==0?row0:kx==1?row1:kx==2?row2:kx==3?row3:row4);        \
        float e1 = (kx==0?row1:kx==1?row2:kx==2?row3:kx==3?row4:row5);        \
        float w = wa[(r-1)*5+kx], u = wb[(r-1)*5+kx];                         \
        vA2=fmaf(e0,w,vA2); vA3=fmaf(e1,w,vA3);                               \
        vB2=fmaf(e0,u,vB2); vB3=fmaf(e1,u,vB3);                               \
      }                                                                       \
    }                                                                         \
  }

template<bool STORE_MM>
__global__ __launch_bounds__(256) void k_conv1_stats(const float* __restrict__ x,
        const float* __restrict__ w1, const float* __restrict__ g1,
        float* __restrict__ part1, float2* __restrict__ c1ext){
  __shared__ float img[8*784];
  __shared__ float wsh[500];
  __shared__ float gsh[20];
  __shared__ float red[4][40];
  int tid = threadIdx.x;
  size_t base = (size_t)blockIdx.x * 8;
  const float4* xv = (const float4*)(x + base*784);
  float4* iv = (float4*)img;
  for (int i=tid;i<1568;i+=256) iv[i] = xv[i];
  for (int i=tid;i<500;i+=256)  wsh[i] = w1[i];
  if (tid < 20) gsh[tid] = g1[tid];
  __syncthreads();
  int lane = tid & 63, wid = tid >> 6;
#pragma unroll 1
  for (int cg=0; cg<10; ++cg){
    float wa[25], wb[25];
#pragma unroll
    for (int k=0;k<25;k++){ wa[k]=wsh[(2*cg)*25+k]; wb[k]=wsh[(2*cg+1)*25+k]; }
    float gA = gsh[2*cg], gB = gsh[2*cg+1];
    float sa=0.f, qa=0.f, sb=0.f, qb=0.f;
#pragma unroll 1
    for (int job=tid; job<8*144; job+=256){
      int li = job/144, pp = job%144;
      int py = pp/12, px = pp%12;
      const float* ip = &img[li*784 + py*56 + px*2];
      CONV1_PATCH_FMA(ip)
      sa += (vA0+vA1)+(vA2+vA3);
      qa = fmaf(vA0,vA0, fmaf(vA1,vA1, fmaf(vA2,vA2, fmaf(vA3,vA3, qa))));
      sb += (vB0+vB1)+(vB2+vB3);
      qb = fmaf(vB0,vB0, fmaf(vB1,vB1, fmaf(vB2,vB2, fmaf(vB3,vB3, qb))));
      if (STORE_MM){
        float mxA = fmaxf(fmaxf(vA0,vA1),fmaxf(vA2,vA3));
        float mnA = fminf(fminf(vA0,vA1),fminf(vA2,vA3));
        float mxB = fmaxf(fmaxf(vB0,vB1),fmaxf(vB2,vB3));
        float mnB = fminf(fminf(vB0,vB1),fminf(vB2,vB3));
        float eA = (gA > 0.f) ? mxA : mnA;
        float eB = (gB > 0.f) ? mxB : mnB;
        c1ext[(size_t)cg*NJOB + (base+li)*144 + pp] = make_float2(eA,eB);
      }
    }
#pragma unroll
    for (int d=32; d>0; d>>=1){
      sa += __shfl_down(sa,d); qa += __shfl_down(qa,d);
      sb += __shfl_down(sb,d); qb += __shfl_down(qb,d);
    }
    if (lane==0){
      red[wid][(2*cg)*2]   = sa; red[wid][(2*cg)*2+1]   = qa;
      red[wid][(2*cg+1)*2] = sb; red[wid][(2*cg+1)*2+1] = qb;
    }
  }
  __syncthreads();
  if (tid < 40)
    part1[blockIdx.x*40 + tid] = red[0][tid]+red[1][tid]+red[2][tid]+red[3][tid];
}

// one block per channel; 256 threads; deterministic fixed-pairing tree
__global__ __launch_bounds__(256) void k_reduce1(const float* __restrict__ part1,
        const float* __restrict__ g, const float* __restrict__ b,
        float* __restrict__ s1t1){
  __shared__ double rs[256], rq[256];
  int c = blockIdx.x;          // 0..19
  int tid = threadIdx.x;
  double s=0.0, q=0.0;
  for (int i=tid;i<1024;i+=256){
    s += (double)part1[i*40 + c*2];
    q += (double)part1[i*40 + c*2 + 1];
  }
  rs[tid]=s; rq[tid]=q;
  __syncthreads();
  for (int d=128; d>0; d>>=1){
    if (tid<d){ rs[tid]+=rs[tid+d]; rq[tid]+=rq[tid+d]; }
    __syncthreads();
  }
  if (tid==0){
    double N = 8192.0*576.0;
    double mean = rs[0]/N, var = rq[0]/N - mean*mean;
    double r = 1.0/sqrt(var + 1e-5);
    double sc = (double)g[c]*r;
    s1t1[c*2]   = (float)sc;
    s1t1[c*2+1] = (float)((double)b[c] - mean*sc);
  }
}

// fallback pass B (recompute): conv1 + threshold + OR-pool, per-job LDS word
__global__ __launch_bounds__(256) void k_conv1_bin(const float* __restrict__ x,
        const float* __restrict__ w1, const float* __restrict__ s1t1,
        unsigned* __restrict__ mask1){
  __shared__ float img[8*784];
  __shared__ float wsh[500];
  __shared__ float st[40];
  __shared__ unsigned lw[8*144];
  int tid = threadIdx.x;
  size_t base = (size_t)blockIdx.x * 8;
  const float4* xv = (const float4*)(x + base*784);
  float4* iv = (float4*)img;
  for (int i=tid;i<1568;i+=256) iv[i] = xv[i];
  for (int i=tid;i<500;i+=256)  wsh[i] = w1[i];
  for (int i=tid;i<8*144;i+=256) lw[i] = 0u;
  if (tid < 40) st[tid] = s1t1[tid];
  __syncthreads();
#pragma unroll 1
  for (int cg=0; cg<10; ++cg){
    float wa[25], wb[25];
#pragma unroll
    for (int k=0;k<25;k++){ wa[k]=wsh[(2*cg)*25+k]; wb[k]=wsh[(2*cg+1)*25+k]; }
    float sA = st[(2*cg)*2],   tA = st[(2*cg)*2+1];
    float sB = st[(2*cg+1)*2], tB = st[(2*cg+1)*2+1];
#pragma unroll 1
    for (int job=tid; job<8*144; job+=256){
      int li = job/144, pp = job%144;
      int py = pp/12, px = pp%12;
      const float* ip = &img[li*784 + py*56 + px*2];
      CONV1_ROWS(ip)
      unsigned bA = (fmaf(vA0,sA,tA) > 0.f) || (fmaf(vA1,sA,tA) > 0.f) ||
                    (fmaf(vA2,sA,tA) > 0.f) || (fmaf(vA3,sA,tA) > 0.f);
      unsigned bB = (fmaf(vB0,sB,tB) > 0.f) || (fmaf(vB1,sB,tB) > 0.f) ||
                    (fmaf(vB2,sB,tB) > 0.f) || (fmaf(vB3,sB,tB) > 0.f);
      lw[job] |= (bA << (2*cg)) | (bB << (2*cg+1));
    }
  }
  __syncthreads();
  for (int i=tid;i<8*144;i+=256){
    int li = i/144, pp = i%144;
    mask1[(base+li)*144 + pp] = lw[i];
  }
}

// lite pass B: read stored extreme, threshold, pack. bit = ext*s+t > 0 (exact)
__global__ __launch_bounds__(256) void k_conv1_bin_lite(const float2* __restrict__ c1ext,
        const float* __restrict__ s1t1, unsigned* __restrict__ mask1){
  __shared__ float st[40];
  int tid = threadIdx.x;
  if (tid < 40) st[tid] = s1t1[tid];
  __syncthreads();
  int J = blockIdx.x*256 + tid;      // grid = 4608 -> exactly NJOB
  unsigned word = 0;
#pragma unroll
  for (int cg=0; cg<10; ++cg){
    float2 v = c1ext[(size_t)cg*NJOB + J];
    float sA = st[4*cg+0], tA = st[4*cg+1];
    float sB = st[4*cg+2], tB = st[4*cg+3];
    word |= ((fmaf(v.x,sA,tA) > 0.f) ? 1u : 0u) << (2*cg);
    word |= ((fmaf(v.y,sB,tB) > 0.f) ? 1u : 0u) << (2*cg+1);
  }
  mask1[J] = word;
}

// ---------------------------------------------------------------------------
// Stage 2: binary conv2. lane = conv position (8x8), wave = image.
// k_conv2: compute S, store S16 ONLY (no in-kernel reduce). Fast path:
// S = popc(m) - 2*popc(m&N), 25 words exactly.
// ---------------------------------------------------------------------------
__global__ __launch_bounds__(256) void k_conv2(const unsigned* __restrict__ mask1,
    const unsigned* __restrict__ wpos, const unsigned* __restrict__ wneg,
    const int* __restrict__ flags2, short* __restrict__ S16){
  __shared__ unsigned m1[4*144];
  __shared__ __align__(16) unsigned wp[1400], wn[1400];   // [50][28] zero-padded
  int tid = threadIdx.x;
  size_t base = (size_t)blockIdx.x * 4;
  bool slow = (flags2[0]|flags2[1]|flags2[2]|flags2[3]|flags2[4]) != 0;
  for (int i=tid;i<4*144;i+=256) m1[i] = mask1[base*144 + i];
  for (int i=tid;i<1400;i+=256){
    int o = i/28, k = i%28;
    wn[i] = (k<25) ? wneg[o*25+k] : 0u;
    if (slow) wp[i] = (k<25) ? wpos[o*25+k] : 0u;
  }
  __syncthreads();
  int lane = tid & 63, wid = tid >> 6;
  int y2 = lane >> 3, x2 = lane & 7;
  unsigned mw[25];
  const unsigned* mrow = &m1[wid*144];
#pragma unroll
  for (int ky=0;ky<5;ky++)
#pragma unroll
    for (int kx=0;kx<5;kx++)
      mw[ky*5+kx] = mrow[(y2+ky)*12 + x2+kx];
  short* sp = &S16[((base+wid)*50)*64 + lane];
  if (!slow){
    int pbase = 0;
#pragma unroll
    for (int k=0;k<25;k++) pbase += __popc(mw[k]);
#pragma unroll 1
    for (int o=0;o<50;o++){
      const uint4* n4 = (const uint4*)&wn[o*28];
      int Sn=0;
#pragma unroll
      for (int g=0; g<6; g++){
        uint4 N = n4[g];
        Sn += __popc(mw[4*g]&N.x) + __popc(mw[4*g+1]&N.y)
            + __popc(mw[4*g+2]&N.z) + __popc(mw[4*g+3]&N.w);
      }
      Sn += __popc(mw[24] & wn[o*28+24]);
      sp[o*64] = (short)(pbase - 2*Sn);
    }
  } else {
#pragma unroll 1
    for (int o=0;o<50;o++){
      const uint4* p4 = (const uint4*)&wp[o*28];
      const uint4* n4 = (const uint4*)&wn[o*28];
      int Sp=0, Sn=0;
#pragma unroll
      for (int g=0; g<6; g++){
        uint4 P = p4[g], N = n4[g];
        Sp += __popc(mw[4*g]&P.x) + __popc(mw[4*g+1]&P.y)
            + __popc(mw[4*g+2]&P.z) + __popc(mw[4*g+3]&P.w);
        Sn += __popc(mw[4*g]&N.x) + __popc(mw[4*g+1]&N.y)
            + __popc(mw[4*g+2]&N.z) + __popc(mw[4*g+3]&N.w);
      }
      Sp += __popc(mw[24] & wp[o*28+24]);
      Sn += __popc(mw[24] & wn[o*28+24]);
      sp[o*64] = (short)(Sp - Sn);
    }
  }
}

// streaming stats over S16: grid 256 blocks x 32 images. wave b covers
// o in {b+4k}; lane = pos; 128B-coalesced interleaved reads.
__global__ __launch_bounds__(256) void k_stats2(const short* __restrict__ S16,
        int* __restrict__ part2){
  int tid = threadIdx.x;
  int lane = tid & 63, wid = tid >> 6;
  const short* p = S16 + (size_t)blockIdx.x * 32 * 3200;
  int rs[13], rq[13];
#pragma unroll
  for (int k=0;k<13;k++){ rs[k]=0; rq[k]=0; }
#pragma unroll 1
  for (int im=0; im<32; ++im){
    const short* q = p + im*3200 + tid;
#pragma unroll
    for (int k=0;k<13;k++){
      if (wid + 4*k < 50){
        int v = q[256*k];
        rs[k] += v; rq[k] += v*v;
      }
    }
  }
#pragma unroll
  for (int k=0;k<13;k++){
    int o = wid + 4*k;
    if (o < 50){
      int s = rs[k], q2 = rq[k];
#pragma unroll
      for (int d=32; d>0; d>>=1){ s += __shfl_down(s,d); q2 += __shfl_down(q2,d); }
      if (lane==0){
        part2[blockIdx.x*100 + o*2]     = s;
        part2[blockIdx.x*100 + o*2 + 1] = q2;
      }
    }
  }
}

// legacy conv2+stats (fallback when S16 doesn't fit): in-kernel reduce
__global__ __launch_bounds__(256) void k_conv2_stats_legacy(const unsigned* __restrict__ mask1,
    const unsigned* __restrict__ wpos, const unsigned* __restrict__ wneg,
    const int* __restrict__ flags2, int* __restrict__ part2){
  __shared__ unsigned m1[4*144];
  __shared__ __align__(16) unsigned wp[1400], wn[1400];
  __shared__ int red[4][100];
  int tid = threadIdx.x;
  size_t base = (size_t)blockIdx.x * 4;
  for (int i=tid;i<4*144;i+=256) m1[i] = mask1[base*144 + i];
  for (int i=tid;i<1400;i+=256){
    int o = i/28, k = i%28;
    wn[i] = (k<25) ? wneg[o*25+k] : 0u;
    wp[i] = (k<25) ? wpos[o*25+k] : 0u;
  }
  __syncthreads();
  int lane = tid & 63, wid = tid >> 6;
  int y2 = lane >> 3, x2 = lane & 7;
  unsigned mw[25];
  const unsigned* mrow = &m1[wid*144];
#pragma unroll
  for (int ky=0;ky<5;ky++)
#pragma unroll
    for (int kx=0;kx<5;kx++)
      mw[ky*5+kx] = mrow[(y2+ky)*12 + x2+kx];
#pragma unroll 1
  for (int o=0;o<50;o++){
    const uint4* p4 = (const uint4*)&wp[o*28];
    const uint4* n4 = (const uint4*)&wn[o*28];
    int Sp=0, Sn=0;
#pragma unroll
    for (int g=0; g<6; g++){
      uint4 P = p4[g], N = n4[g];
      Sp += __popc(mw[4*g]&P.x) + __popc(mw[4*g+1]&P.y)
          + __popc(mw[4*g+2]&P.z) + __popc(mw[4*g+3]&P.w);
      Sn += __popc(mw[4*g]&N.x) + __popc(mw[4*g+1]&N.y)
          + __popc(mw[4*g+2]&N.z) + __popc(mw[4*g+3]&N.w);
    }
    Sp += __popc(mw[24] & wp[o*28+24]);
    Sn += __popc(mw[24] & wn[o*28+24]);
    int S = Sp - Sn;
    int rs = S, rq = S*S;
#pragma unroll
    for (int d=32; d>0; d>>=1){ rs += __shfl_down(rs,d); rq += __shfl_down(rq,d); }
    if (lane==0){ red[wid][o*2] = rs; red[wid][o*2+1] = rq; }
  }
  __syncthreads();
  if (tid < 100)
    part2[blockIdx.x*100 + tid] = red[0][tid]+red[1][tid]+red[2][tid]+red[3][tid];
}

// one block per channel; sums nchunk partial entries (layout [chunk][100])
__global__ __launch_bounds__(256) void k_reduce2(const int* __restrict__ part2,
        int nchunk, const float* __restrict__ alpha2, const float* __restrict__ g,
        const float* __restrict__ b, float* __restrict__ s2t2){
  __shared__ long long rs[256], rq[256];
  int o = blockIdx.x;          // 0..49
  int tid = threadIdx.x;
  long long s=0, q=0;
  for (int i=tid;i<nchunk;i+=256){
    s += part2[i*100 + o*2];
    q += part2[i*100 + o*2 + 1];
  }
  rs[tid]=s; rq[tid]=q;
  __syncthreads();
  for (int d=128; d>0; d>>=1){
    if (tid<d){ rs[tid]+=rs[tid+d]; rq[tid]+=rq[tid+d]; }
    __syncthreads();
  }
  if (tid==0){
    double N = 8192.0*64.0;
    double meanS = (double)rs[0]/N, E2 = (double)rq[0]/N;
    double varS = E2 - meanS*meanS;
    double a = (double)alpha2[o];
    double mean_g = a*meanS, var_g = a*a*varS;
    double r = 1.0/sqrt(var_g + 1e-5);
    double sc = (double)g[o]*r;
    s2t2[o*2]   = (float)(sc*a);                      // applied to integer S
    s2t2[o*2+1] = (float)((double)b[o] - mean_g*sc);
  }
}

#define BIN2_POOL_BODY                                                        \
    unsigned long long bal = __ballot(cond);                                  \
    unsigned long long t4 = bal | (bal>>1) | (bal>>8) | (bal>>9);             \
    bool pb = (lane < 16) && ((t4 >> (16*(lane>>2) + 2*(lane&3))) & 1ull);    \
    unsigned long long bal2 = __ballot(pb);                                   \
    if (lane==0){                                                             \
      unsigned pooled16 = (unsigned)(bal2 & 0xFFFFull);                       \
      lw[wid*25 + (o>>1)] |= pooled16 << (16*(o&1));                          \
    }

// fallback pass B (recompute, exact P/N)
__global__ __launch_bounds__(256) void k_bin2(const unsigned* __restrict__ mask1,
    const unsigned* __restrict__ wpos, const unsigned* __restrict__ wneg,
    const float* __restrict__ s2t2, unsigned* __restrict__ mask2){
  __shared__ unsigned m1[4*144];
  __shared__ __align__(16) unsigned wp[1400], wn[1400];
  __shared__ float st[100];
  __shared__ unsigned lw[100];
  int tid = threadIdx.x;
  size_t base = (size_t)blockIdx.x * 4;
  for (int i=tid;i<4*144;i+=256) m1[i] = mask1[base*144 + i];
  for (int i=tid;i<1400;i+=256){
    int o = i/28, k = i%28;
    wp[i] = (k<25) ? wpos[o*25+k] : 0u;
    wn[i] = (k<25) ? wneg[o*25+k] : 0u;
  }
  if (tid < 100){ st[tid] = s2t2[tid]; lw[tid] = 0u; }
  __syncthreads();
  int lane = tid & 63, wid = tid >> 6;
  int y2 = lane >> 3, x2 = lane & 7;
  unsigned mw[25];
  const unsigned* mrow = &m1[wid*144];
#pragma unroll
  for (int ky=0;ky<5;ky++)
#pragma unroll
    for (int kx=0;kx<5;kx++)
      mw[ky*5+kx] = mrow[(y2+ky)*12 + x2+kx];
#pragma unroll 1
  for (int o=0;o<50;o++){
    const uint4* p4 = (const uint4*)&wp[o*28];
    const uint4* n4 = (const uint4*)&wn[o*28];
    int Sp=0, Sn=0;
#pragma unroll
    for (int g=0; g<6; g++){
      uint4 P = p4[g], N = n4[g];
      Sp += __popc(mw[4*g]&P.x) + __popc(mw[4*g+1]&P.y)
          + __popc(mw[4*g+2]&P.z) + __popc(mw[4*g+3]&P.w);
      Sn += __popc(mw[4*g]&N.x) + __popc(mw[4*g+1]&N.y)
          + __popc(mw[4*g+2]&N.z) + __popc(mw[4*g+3]&N.w);
    }
    Sp += __popc(mw[24] & wp[o*28+24]);
    Sn += __popc(mw[24] & wn[o*28+24]);
    int S = Sp - Sn;
    bool cond = fmaf((float)S, st[o*2], st[o*2+1]) > 0.f;
    BIN2_POOL_BODY
  }
  __syncthreads();
  if (tid < 100) mask2[base*25 + tid] = lw[tid];
}

// lite pass B: read S16, threshold, ballot-pool, pack
__global__ __launch_bounds__(256) void k_bin2_lite(const short* __restrict__ S16,
    const float* __restrict__ s2t2, unsigned* __restrict__ mask2){
  __shared__ float st[100];
  __shared__ unsigned lw[100];
  int tid = threadIdx.x;
  if (tid < 100){ st[tid] = s2t2[tid]; lw[tid] = 0u; }
  __syncthreads();
  int lane = tid & 63, wid = tid >> 6;
  size_t img = (size_t)blockIdx.x*4 + wid;
#pragma unroll 1
  for (int o=0;o<50;o++){
    int S = S16[(img*50 + o)*64 + lane];
    bool cond = fmaf((float)S, st[o*2], st[o*2+1]) > 0.f;
    BIN2_POOL_BODY
  }
  __syncthreads();
  if (tid < 100) mask2[blockIdx.x*100 + tid] = lw[tid];
}

// ---------------------------------------------------------------------------
// Stage 3: binary fc1 (800 -> 500). 8 img/block, grid 1024. Fast path uses
// S = popc(m) - 2*popc(m&N) when no zero weights (flags3).
// ---------------------------------------------------------------------------
__global__ __launch_bounds__(256) void k_fc1(const unsigned* __restrict__ mask2,
    const unsigned* __restrict__ wpos, const unsigned* __restrict__ wneg,
    const int* __restrict__ flags3, short* __restrict__ S3){
  __shared__ unsigned m2s[8*25];
  __shared__ short s3s[8*500];
  int tid = threadIdx.x;
  size_t base = (size_t)blockIdx.x * 8;
  for (int i=tid;i<200;i+=256) m2s[i] = mask2[base*25 + i];
  __syncthreads();
  int f = 0;
  for (int i=0;i<49;i++) f |= flags3[i];
  int bl = tid & 7;
  int jg = tid >> 3;   // 32 groups
  const unsigned* mrow = &m2s[bl*25];
  if (f == 0){
    int pbase = 0;
#pragma unroll
    for (int w=0;w<25;w++) pbase += __popc(mrow[w]);
#pragma unroll 1
    for (int j=jg; j<500; j+=32){
      const unsigned* n = &wneg[j*25];
      int Sn = 0;
#pragma unroll
      for (int w=0;w<25;w++) Sn += __popc(mrow[w] & n[w]);
      s3s[bl*500 + j] = (short)(pbase - 2*Sn);
    }
  } else {
#pragma unroll 1
    for (int j=jg; j<500; j+=32){
      const unsigned* p = &wpos[j*25];
      const unsigned* n = &wneg[j*25];
      int S = 0;
#pragma unroll
      for (int w=0;w<25;w++){
        unsigned m = mrow[w];
        S += __popc(m & p[w]) - __popc(m & n[w]);
      }
      s3s[bl*500 + j] = (short)S;
    }
  }
  __syncthreads();
  for (int i=tid;i<8*500;i+=256) S3[base*500 + i] = s3s[i];
}

// per-feature batch stats of S3 (int, exact): 64 images/block, 128 blocks
__global__ __launch_bounds__(256) void k_stats3(const short* __restrict__ S3,
                                                int* __restrict__ part3){
  int tid = threadIdx.x;
  const short* p = &S3[(size_t)blockIdx.x * 64 * 500];
  int s0=0,q0=0,s1=0,q1=0;
  for (int b=0;b<64;b++){
    int v0 = p[b*500 + tid];
    s0 += v0; q0 += v0*v0;
    if (tid < 244){
      int v1 = p[b*500 + tid + 256];
      s1 += v1; q1 += v1*v1;
    }
  }
  part3[blockIdx.x*1000 + tid*2]     = s0;
  part3[blockIdx.x*1000 + tid*2 + 1] = q0;
  if (tid < 244){
    part3[blockIdx.x*1000 + (tid+256)*2]     = s1;
    part3[blockIdx.x*1000 + (tid+256)*2 + 1] = q1;
  }
}

__global__ void k_reduce3(const int* __restrict__ part3, const float* __restrict__ alpha3,
                          const float* __restrict__ g, const float* __restrict__ b,
                          float* __restrict__ s3t3){
  int j = blockIdx.x*256 + threadIdx.x;
  if (j >= 500) return;
  long long s=0, q=0;
  for (int i=0;i<128;i++){
    s += part3[i*1000 + j*2];
    q += part3[i*1000 + j*2 + 1];
  }
  double N = 8192.0;
  double meanS = (double)s/N, E2 = (double)q/N;
  double varS = E2 - meanS*meanS;
  double a = (double)alpha3[j];
  double mean_u = a*meanS, var_u = a*a*varS;
  double r = 1.0/sqrt(var_u + 1e-5);
  double sc = (double)g[j]*r;
  s3t3[j*2]   = (float)(sc*a);
  s3t3[j*2+1] = (float)((double)b[j] - mean_u*sc);
}

// h3 = relu(s3*S3 + t3); out = h3 @ fc2_w^T + fc2_b
// 32 img/block, 8 threads per image, shfl_xor(1,2,4) reduce. grid 256.
__global__ __launch_bounds__(256) void k_final(const short* __restrict__ S3,
    const float* __restrict__ s3t3, const float* __restrict__ fc2w,
    const float* __restrict__ fc2b, float* __restrict__ out){
  __shared__ float w[5000];
  __shared__ float st[1000];
  __shared__ float bias[10];
  int tid = threadIdx.x;
  for (int i=tid;i<5000;i+=256) w[i] = fc2w[i];
  for (int i=tid;i<1000;i+=256) st[i] = s3t3[i];
  if (tid<10) bias[tid] = fc2b[tid];
  __syncthreads();
  int sub = tid & 7;                 // 8 threads per image
  int li  = tid >> 3;                // 0..31
  size_t b = (size_t)blockIdx.x*32 + li;
  const short* sp = &S3[b*500];
  float acc[10];
#pragma unroll
  for (int m=0;m<10;m++) acc[m] = 0.f;
#pragma unroll 1
  for (int j=sub; j<500; j+=8){
    float h = fmaf((float)sp[j], st[j*2], st[j*2+1]);
    h = fmaxf(h, 0.f);
#pragma unroll
    for (int m=0;m<10;m++) acc[m] = fmaf(h, w[m*500+j], acc[m]);
  }
#pragma unroll
  for (int m=0;m<10;m++){
    float v = acc[m];
    v += __shfl_xor(v, 1);
    v += __shfl_xor(v, 2);
    v += __shfl_xor(v, 4);
    acc[m] = v;
  }
  if (sub == 0){
#pragma unroll
    for (int m=0;m<10;m++) out[b*10 + m] = acc[m] + bias[m];
  }
}

// ---------------------------------------------------------------------------
extern "C" void kernel_launch(void* const* d_in, const int* in_sizes, int n_in,
                              void* d_out, int out_size, void* d_ws, size_t ws_size,
                              hipStream_t stream){
  const float* x    = (const float*)d_in[0];
  const float* w1   = (const float*)d_in[1];
  const float* bn1g = (const float*)d_in[2];
  const float* bn1b = (const float*)d_in[3];
  const float* w2   = (const float*)d_in[4];
  const float* bn2g = (const float*)d_in[5];
  const float* bn2b = (const float*)d_in[6];
  const float* w3   = (const float*)d_in[7];
  const float* bn3g = (const float*)d_in[8];
  const float* bn3b = (const float*)d_in[9];
  const float* w4   = (const float*)d_in[10];
  const float* b4   = (const float*)d_in[11];
  float* out = (float*)d_out;
  (void)in_sizes; (void)n_in; (void)out_size;

  char* wsb = (char*)d_ws;
  size_t off = 0;
  auto alloc = [&](size_t n){ size_t o = off; off = (off + n + 255) & ~(size_t)255; return o; };
  float*    s1t1   = (float*)(wsb + alloc(40*sizeof(float)));
  float*    s2t2   = (float*)(wsb + alloc(100*sizeof(float)));
  float*    s3t3   = (float*)(wsb + alloc(1000*sizeof(float)));
  float*    alpha2 = (float*)(wsb + alloc(50*sizeof(float)));
  float*    alpha3 = (float*)(wsb + alloc(500*sizeof(float)));
  int*      flags2 = (int*)(wsb + alloc(5*4));
  int*      flags3 = (int*)(wsb + alloc(49*4));
  unsigned* wpos2  = (unsigned*)(wsb + alloc(1250*4));
  unsigned* wneg2  = (unsigned*)(wsb + alloc(1250*4));
  unsigned* wpos3  = (unsigned*)(wsb + alloc(12500*4));
  unsigned* wneg3  = (unsigned*)(wsb + alloc(12500*4));
  float*    part1  = (float*)(wsb + alloc(1024*40*4));
  int*      part2  = (int*)(wsb + alloc(2048*100*4));
  int*      part3  = (int*)(wsb + alloc(128*1000*4));
  unsigned* mask1  = (unsigned*)(wsb + alloc((size_t)BATCH*144*4));
  unsigned* mask2  = (unsigned*)(wsb + alloc((size_t)BATCH*25*4));
  short*    S3     = (short*)(wsb + alloc((size_t)BATCH*500*2));
  // optional staging buffers (runtime-gated on ws_size)
  short*    S16    = (short*)(wsb + alloc((size_t)BATCH*50*64*2));
  bool useS16 = (ws_size >= off);
  float2*   c1ext  = (float2*)(wsb + alloc((size_t)10*NJOB*8));
  bool useMM  = (ws_size >= off);

  hipLaunchKernelGGL(k_pack, dim3(54), dim3(256), 0, stream,
                     w2, w3, wpos2, wneg2, alpha2, wpos3, wneg3, alpha3, flags2, flags3);
  if (useMM)
    hipLaunchKernelGGL(HIP_KERNEL_NAME(k_conv1_stats<true>),  dim3(1024), dim3(256), 0, stream, x, w1, bn1g, part1, c1ext);
  else
    hipLaunchKernelGGL(HIP_KERNEL_NAME(k_conv1_stats<false>), dim3(1024), dim3(256), 0, stream, x, w1, bn1g, part1, c1ext);
  hipLaunchKernelGGL(k_reduce1,      dim3(20),    dim3(256), 0, stream, part1, bn1g, bn1b, s1t1);
  if (useMM)
    hipLaunchKernelGGL(k_conv1_bin_lite, dim3(4608), dim3(256), 0, stream, c1ext, s1t1, mask1);
  else
    hipLaunchKernelGGL(k_conv1_bin,  dim3(1024),  dim3(256), 0, stream, x, w1, s1t1, mask1);
  if (useS16){
    hipLaunchKernelGGL(k_conv2,      dim3(2048),  dim3(256), 0, stream, mask1, wpos2, wneg2, flags2, S16);
    hipLaunchKernelGGL(k_stats2,     dim3(256),   dim3(256), 0, stream, S16, part2);
    hipLaunchKernelGGL(k_reduce2,    dim3(50),    dim3(256), 0, stream, part2, 256, alpha2, bn2g, bn2b, s2t2);
    hipLaunchKernelGGL(k_bin2_lite,  dim3(2048),  dim3(256), 0, stream, S16, s2t2, mask2);
  } else {
    hipLaunchKernelGGL(k_conv2_stats_legacy, dim3(2048), dim3(256), 0, stream, mask1, wpos2, wneg2, flags2, part2);
    hipLaunchKernelGGL(k_reduce2,    dim3(50),    dim3(256), 0, stream, part2, 2048, alpha2, bn2g, bn2b, s2t2);
    hipLaunchKernelGGL(k_bin2,       dim3(2048),  dim3(256), 0, stream, mask1, wpos2, wneg2, s2t2, mask2);
  }
  hipLaunchKernelGGL(k_fc1,          dim3(1024),  dim3(256), 0, stream, mask2, wpos3, wneg3, flags3, S3);
  hipLaunchKernelGGL(k_stats3,       dim3(128),   dim3(256), 0, stream, S3, part3);
  hipLaunchKernelGGL(k_reduce3,      dim3(2),     dim3(256), 0, stream, part3, alpha3, bn3g, bn3b, s3t3);
  hipLaunchKernelGGL(k_final,        dim3(256),   dim3(256), 0, stream, S3, s3t3, w4, b4, out);
}

// Round 15
// 351.601 us; speedup vs baseline: 1.0419x; 1.0419x over previous
//
#include <hip/hip_runtime.h>
#include <stdint.h>

#define BATCH 8192
#define NJOB  1179648   // 8192*144

// ---------------------------------------------------------------------------
// Stage 0 (merged): pack binarized weights + alphas + per-block zero flags.
// ---------------------------------------------------------------------------
__global__ __launch_bounds__(256) void k_pack(const float* __restrict__ w2,
    const float* __restrict__ w3, unsigned* __restrict__ wpos2,
    unsigned* __restrict__ wneg2, float* __restrict__ alpha2,
    unsigned* __restrict__ wpos3, unsigned* __restrict__ wneg3,
    float* __restrict__ alpha3, int* __restrict__ flags2, int* __restrict__ flags3){
  __shared__ int zf;
  int tid = threadIdx.x;
  if (tid == 0) zf = 0;
  __syncthreads();
  if (blockIdx.x < 5){
    int t = blockIdx.x*256 + tid;
    int had0 = 0;
    if (t < 1250){                     // t = o*25 + k
      int o = t/25, k = t%25;
      unsigned p=0, n=0;
      for (int i=0;i<20;i++){
        float v = w2[(o*20+i)*25 + k];
        if (v > 0.f) p |= 1u<<i;
        else if (v < 0.f) n |= 1u<<i;
        else had0 = 1;
      }
      wpos2[t] = p; wneg2[t] = n;
    }
    if (t < 50){
      float s = 0.f;
      for (int i=0;i<500;i++) s += fabsf(w2[t*500+i]);
      alpha2[t] = s / 500.f;
    }
    if (had0) atomicOr(&zf, 1);
    __syncthreads();
    if (tid == 0) flags2[blockIdx.x] = zf;
  } else {
    int t = (blockIdx.x-5)*256 + tid;
    int had0 = 0;
    if (t < 12500){                    // t = j*25 + w
      int j = t/25, w = t%25;
      unsigned p=0, n=0;
      for (int bb=0;bb<32;bb++){
        float v = w3[j*800 + w*32 + bb];
        if (v > 0.f) p |= 1u<<bb;
        else if (v < 0.f) n |= 1u<<bb;
        else had0 = 1;
      }
      wpos3[t] = p; wneg3[t] = n;
    }
    if (t < 500){
      float s = 0.f;
      for (int i=0;i<800;i++) s += fabsf(w3[t*800+i]);
      alpha3[t] = s / 800.f;
    }
    if (had0) atomicOr(&zf, 1);
    __syncthreads();
    if (tid == 0) flags3[blockIdx.x-5] = zf;
  }
}

// ---------------------------------------------------------------------------
// Stage 1: conv1 (fp32). 8 images/block, grid 1024. Channel-pair outer loop,
// row-streaming inner conv (round-11 form: best measured, 86us).
// ---------------------------------------------------------------------------

#define CONV1_ROWS(IPTR)                                                      \
  float vA0=0.f,vA1=0.f,vA2=0.f,vA3=0.f;                                      \
  float vB0=0.f,vB1=0.f,vB2=0.f,vB3=0.f;                                      \
  _Pragma("unroll")                                                           \
  for (int r=0;r<6;r++){                                                      \
    const float2* rp = (const float2*)((IPTR) + r*28);                        \
    float2 p0 = rp[0], p1 = rp[1], p2 = rp[2];                                \
    float row0=p0.x, row1=p0.y, row2=p1.x, row3=p1.y, row4=p2.x, row5=p2.y;   \
    if (r<5){                                                                 \
      _Pragma("unroll")                                                       \
      for (int kx=0;kx<5;kx++){                                               \
        float e0 = (kx==0?row0:kx==1?row1:kx==2?row2:kx==3?row3:row4);        \
        float e1 = (kx==0?row1:kx==1?row2:kx==2?row3:kx==3?row4:row5);        \
        float w = wa[r*5+kx], u = wb[r*5+kx];                                 \
        vA0=fmaf(e0,w,vA0); vA1=fmaf(e1,w,vA1);                               \
        vB0=fmaf(e0,u,vB0); vB1=fmaf(e1,u,vB1);                               \
      }                                                                       \
    }                                                                         \
    if (r>0){                                                                 \
      _Pragma("unroll")                                                       \
      for (int kx=0;kx<5;kx++){                                               \
        float e0 = (kx==0?row0:kx==1?row1:kx==2?row2:kx==3?row3:row4);        \
        float e1 = (kx==0?row1:kx==1?row2:kx==2?row3:kx==3?row4:row5);        \
        float w = wa[(r-1)*5+kx], u = wb[(r-1)*5+kx];                         \
        vA2=fmaf(e0,w,vA2); vA3=fmaf(e1,w,vA3);                               \
        vB2=fmaf(e0,u,vB2); vB3=fmaf(e1,u,vB3);                               \
      }                                                                       \
    }                                                                         \
  }

template<bool STORE_MM>
__global__ __launch_bounds__(256) void k_conv1_stats(const float* __restrict__ x,
        const float* __restrict__ w1, const float* __restrict__ g1,
        float* __restrict__ part1, float2* __restrict__ c1ext){
  __shared__ float img[8*784];
  __shared__ float wsh[500];
  __shared__ float gsh[20];
  __shared__ float red[4][40];
  int tid = threadIdx.x;
  size_t base = (size_t)blockIdx.x * 8;
  const float4* xv = (const float4*)(x + base*784);
  float4* iv = (float4*)img;
  for (int i=tid;i<1568;i+=256) iv[i] = xv[i];
  for (int i=tid;i<500;i+=256)  wsh[i] = w1[i];
  if (tid < 20) gsh[tid] = g1[tid];
  __syncthreads();
  int lane = tid & 63, wid = tid >> 6;
#pragma unroll 1
  for (int cg=0; cg<10; ++cg){
    float wa[25], wb[25];
#pragma unroll
    for (int k=0;k<25;k++){ wa[k]=wsh[(2*cg)*25+k]; wb[k]=wsh[(2*cg+1)*25+k]; }
    float gA = gsh[2*cg], gB = gsh[2*cg+1];
    float sa=0.f, qa=0.f, sb=0.f, qb=0.f;
#pragma unroll 1
    for (int job=tid; job<8*144; job+=256){
      int li = job/144, pp = job%144;
      int py = pp/12, px = pp%12;
      const float* ip = &img[li*784 + py*56 + px*2];
      CONV1_ROWS(ip)
      sa += (vA0+vA1)+(vA2+vA3);
      qa = fmaf(vA0,vA0, fmaf(vA1,vA1, fmaf(vA2,vA2, fmaf(vA3,vA3, qa))));
      sb += (vB0+vB1)+(vB2+vB3);
      qb = fmaf(vB0,vB0, fmaf(vB1,vB1, fmaf(vB2,vB2, fmaf(vB3,vB3, qb))));
      if (STORE_MM){
        float mxA = fmaxf(fmaxf(vA0,vA1),fmaxf(vA2,vA3));
        float mnA = fminf(fminf(vA0,vA1),fminf(vA2,vA3));
        float mxB = fmaxf(fmaxf(vB0,vB1),fmaxf(vB2,vB3));
        float mnB = fminf(fminf(vB0,vB1),fminf(vB2,vB3));
        float eA = (gA > 0.f) ? mxA : mnA;
        float eB = (gB > 0.f) ? mxB : mnB;
        c1ext[(size_t)cg*NJOB + (base+li)*144 + pp] = make_float2(eA,eB);
      }
    }
#pragma unroll
    for (int d=32; d>0; d>>=1){
      sa += __shfl_down(sa,d); qa += __shfl_down(qa,d);
      sb += __shfl_down(sb,d); qb += __shfl_down(qb,d);
    }
    if (lane==0){
      red[wid][(2*cg)*2]   = sa; red[wid][(2*cg)*2+1]   = qa;
      red[wid][(2*cg+1)*2] = sb; red[wid][(2*cg+1)*2+1] = qb;
    }
  }
  __syncthreads();
  if (tid < 40)
    part1[blockIdx.x*40 + tid] = red[0][tid]+red[1][tid]+red[2][tid]+red[3][tid];
}

// one block per channel; 256 threads; deterministic fixed-pairing tree
__global__ __launch_bounds__(256) void k_reduce1(const float* __restrict__ part1,
        const float* __restrict__ g, const float* __restrict__ b,
        float* __restrict__ s1t1){
  __shared__ double rs[256], rq[256];
  int c = blockIdx.x;          // 0..19
  int tid = threadIdx.x;
  double s=0.0, q=0.0;
  for (int i=tid;i<1024;i+=256){
    s += (double)part1[i*40 + c*2];
    q += (double)part1[i*40 + c*2 + 1];
  }
  rs[tid]=s; rq[tid]=q;
  __syncthreads();
  for (int d=128; d>0; d>>=1){
    if (tid<d){ rs[tid]+=rs[tid+d]; rq[tid]+=rq[tid+d]; }
    __syncthreads();
  }
  if (tid==0){
    double N = 8192.0*576.0;
    double mean = rs[0]/N, var = rq[0]/N - mean*mean;
    double r = 1.0/sqrt(var + 1e-5);
    double sc = (double)g[c]*r;
    s1t1[c*2]   = (float)sc;
    s1t1[c*2+1] = (float)((double)b[c] - mean*sc);
  }
}

// fallback pass B (recompute): conv1 + threshold + OR-pool, per-job LDS word
__global__ __launch_bounds__(256) void k_conv1_bin(const float* __restrict__ x,
        const float* __restrict__ w1, const float* __restrict__ s1t1,
        unsigned* __restrict__ mask1){
  __shared__ float img[8*784];
  __shared__ float wsh[500];
  __shared__ float st[40];
  __shared__ unsigned lw[8*144];
  int tid = threadIdx.x;
  size_t base = (size_t)blockIdx.x * 8;
  const float4* xv = (const float4*)(x + base*784);
  float4* iv = (float4*)img;
  for (int i=tid;i<1568;i+=256) iv[i] = xv[i];
  for (int i=tid;i<500;i+=256)  wsh[i] = w1[i];
  for (int i=tid;i<8*144;i+=256) lw[i] = 0u;
  if (tid < 40) st[tid] = s1t1[tid];
  __syncthreads();
#pragma unroll 1
  for (int cg=0; cg<10; ++cg){
    float wa[25], wb[25];
#pragma unroll
    for (int k=0;k<25;k++){ wa[k]=wsh[(2*cg)*25+k]; wb[k]=wsh[(2*cg+1)*25+k]; }
    float sA = st[(2*cg)*2],   tA = st[(2*cg)*2+1];
    float sB = st[(2*cg+1)*2], tB = st[(2*cg+1)*2+1];
#pragma unroll 1
    for (int job=tid; job<8*144; job+=256){
      int li = job/144, pp = job%144;
      int py = pp/12, px = pp%12;
      const float* ip = &img[li*784 + py*56 + px*2];
      CONV1_ROWS(ip)
      unsigned bA = (fmaf(vA0,sA,tA) > 0.f) || (fmaf(vA1,sA,tA) > 0.f) ||
                    (fmaf(vA2,sA,tA) > 0.f) || (fmaf(vA3,sA,tA) > 0.f);
      unsigned bB = (fmaf(vB0,sB,tB) > 0.f) || (fmaf(vB1,sB,tB) > 0.f) ||
                    (fmaf(vB2,sB,tB) > 0.f) || (fmaf(vB3,sB,tB) > 0.f);
      lw[job] |= (bA << (2*cg)) | (bB << (2*cg+1));
    }
  }
  __syncthreads();
  for (int i=tid;i<8*144;i+=256){
    int li = i/144, pp = i%144;
    mask1[(base+li)*144 + pp] = lw[i];
  }
}

// ---------------------------------------------------------------------------
// Stage 2 FUSED: mask1 computed in-block from c1ext, then popcount -> S16.
// ---------------------------------------------------------------------------
__global__ __launch_bounds__(256) void k_conv2f(const float2* __restrict__ c1ext,
    const float* __restrict__ s1t1, const unsigned* __restrict__ wpos,
    const unsigned* __restrict__ wneg, const int* __restrict__ flags2,
    short* __restrict__ S16){
  __shared__ unsigned m1[4*144];
  __shared__ float st[40];
  __shared__ __align__(16) unsigned wp[1400], wn[1400];   // [50][28] zero-padded
  int tid = threadIdx.x;
  size_t base = (size_t)blockIdx.x * 4;
  bool slow = (flags2[0]|flags2[1]|flags2[2]|flags2[3]|flags2[4]) != 0;
  if (tid < 40) st[tid] = s1t1[tid];
  for (int i=tid;i<1400;i+=256){
    int o = i/28, k = i%28;
    wn[i] = (k<25) ? wneg[o*25+k] : 0u;
    if (slow) wp[i] = (k<25) ? wpos[o*25+k] : 0u;
  }
  __syncthreads();
  // phase A: binarize conv1 output (threshold on stored extreme)
  for (int job=tid; job<4*144; job+=256){
    int li = job/144, pp = job%144;
    unsigned word = 0;
#pragma unroll
    for (int cg=0; cg<10; ++cg){
      float2 v = c1ext[(size_t)cg*NJOB + (base+li)*144 + pp];
      word |= ((fmaf(v.x, st[4*cg+0], st[4*cg+1]) > 0.f) ? 1u : 0u) << (2*cg);
      word |= ((fmaf(v.y, st[4*cg+2], st[4*cg+3]) > 0.f) ? 1u : 0u) << (2*cg+1);
    }
    m1[job] = word;
  }
  __syncthreads();
  // phase B: binary conv2 popcount
  int lane = tid & 63, wid = tid >> 6;
  int y2 = lane >> 3, x2 = lane & 7;
  unsigned mw[25];
  const unsigned* mrow = &m1[wid*144];
#pragma unroll
  for (int ky=0;ky<5;ky++)
#pragma unroll
    for (int kx=0;kx<5;kx++)
      mw[ky*5+kx] = mrow[(y2+ky)*12 + x2+kx];
  short* sp = &S16[((base+wid)*50)*64 + lane];
  if (!slow){
    int pbase = 0;
#pragma unroll
    for (int k=0;k<25;k++) pbase += __popc(mw[k]);
#pragma unroll 1
    for (int o=0;o<50;o++){
      const uint4* n4 = (const uint4*)&wn[o*28];
      int Sn=0;
#pragma unroll
      for (int g=0; g<6; g++){
        uint4 N = n4[g];
        Sn += __popc(mw[4*g]&N.x) + __popc(mw[4*g+1]&N.y)
            + __popc(mw[4*g+2]&N.z) + __popc(mw[4*g+3]&N.w);
      }
      Sn += __popc(mw[24] & wn[o*28+24]);
      sp[o*64] = (short)(pbase - 2*Sn);
    }
  } else {
#pragma unroll 1
    for (int o=0;o<50;o++){
      const uint4* p4 = (const uint4*)&wp[o*28];
      const uint4* n4 = (const uint4*)&wn[o*28];
      int Sp=0, Sn=0;
#pragma unroll
      for (int g=0; g<6; g++){
        uint4 P = p4[g], N = n4[g];
        Sp += __popc(mw[4*g]&P.x) + __popc(mw[4*g+1]&P.y)
            + __popc(mw[4*g+2]&P.z) + __popc(mw[4*g+3]&P.w);
        Sn += __popc(mw[4*g]&N.x) + __popc(mw[4*g+1]&N.y)
            + __popc(mw[4*g+2]&N.z) + __popc(mw[4*g+3]&N.w);
      }
      Sp += __popc(mw[24] & wp[o*28+24]);
      Sn += __popc(mw[24] & wn[o*28+24]);
      sp[o*64] = (short)(Sp - Sn);
    }
  }
}

// legacy conv2 from mask1 (fallback when !useMM): S16 only
__global__ __launch_bounds__(256) void k_conv2(const unsigned* __restrict__ mask1,
    const unsigned* __restrict__ wpos, const unsigned* __restrict__ wneg,
    const int* __restrict__ flags2, short* __restrict__ S16){
  __shared__ unsigned m1[4*144];
  __shared__ __align__(16) unsigned wp[1400], wn[1400];
  int tid = threadIdx.x;
  size_t base = (size_t)blockIdx.x * 4;
  bool slow = (flags2[0]|flags2[1]|flags2[2]|flags2[3]|flags2[4]) != 0;
  for (int i=tid;i<4*144;i+=256) m1[i] = mask1[base*144 + i];
  for (int i=tid;i<1400;i+=256){
    int o = i/28, k = i%28;
    wn[i] = (k<25) ? wneg[o*25+k] : 0u;
    if (slow) wp[i] = (k<25) ? wpos[o*25+k] : 0u;
  }
  __syncthreads();
  int lane = tid & 63, wid = tid >> 6;
  int y2 = lane >> 3, x2 = lane & 7;
  unsigned mw[25];
  const unsigned* mrow = &m1[wid*144];
#pragma unroll
  for (int ky=0;ky<5;ky++)
#pragma unroll
    for (int kx=0;kx<5;kx++)
      mw[ky*5+kx] = mrow[(y2+ky)*12 + x2+kx];
  short* sp = &S16[((base+wid)*50)*64 + lane];
  if (!slow){
    int pbase = 0;
#pragma unroll
    for (int k=0;k<25;k++) pbase += __popc(mw[k]);
#pragma unroll 1
    for (int o=0;o<50;o++){
      const uint4* n4 = (const uint4*)&wn[o*28];
      int Sn=0;
#pragma unroll
      for (int g=0; g<6; g++){
        uint4 N = n4[g];
        Sn += __popc(mw[4*g]&N.x) + __popc(mw[4*g+1]&N.y)
            + __popc(mw[4*g+2]&N.z) + __popc(mw[4*g+3]&N.w);
      }
      Sn += __popc(mw[24] & wn[o*28+24]);
      sp[o*64] = (short)(pbase - 2*Sn);
    }
  } else {
#pragma unroll 1
    for (int o=0;o<50;o++){
      const uint4* p4 = (const uint4*)&wp[o*28];
      const uint4* n4 = (const uint4*)&wn[o*28];
      int Sp=0, Sn=0;
#pragma unroll
      for (int g=0; g<6; g++){
        uint4 P = p4[g], N = n4[g];
        Sp += __popc(mw[4*g]&P.x) + __popc(mw[4*g+1]&P.y)
            + __popc(mw[4*g+2]&P.z) + __popc(mw[4*g+3]&P.w);
        Sn += __popc(mw[4*g]&N.x) + __popc(mw[4*g+1]&N.y)
            + __popc(mw[4*g+2]&N.z) + __popc(mw[4*g+3]&N.w);
      }
      Sp += __popc(mw[24] & wp[o*28+24]);
      Sn += __popc(mw[24] & wn[o*28+24]);
      sp[o*64] = (short)(Sp - Sn);
    }
  }
}

// streaming stats over S16: grid 256 blocks x 32 images; 128B-coalesced.
__global__ __launch_bounds__(256) void k_stats2(const short* __restrict__ S16,
        int* __restrict__ part2){
  int tid = threadIdx.x;
  int lane = tid & 63, wid = tid >> 6;
  const short* p = S16 + (size_t)blockIdx.x * 32 * 3200;
  int rs[13], rq[13];
#pragma unroll
  for (int k=0;k<13;k++){ rs[k]=0; rq[k]=0; }
#pragma unroll 1
  for (int im=0; im<32; ++im){
    const short* q = p + im*3200 + tid;
#pragma unroll
    for (int k=0;k<13;k++){
      if (wid + 4*k < 50){
        int v = q[256*k];
        rs[k] += v; rq[k] += v*v;
      }
    }
  }
#pragma unroll
  for (int k=0;k<13;k++){
    int o = wid + 4*k;
    if (o < 50){
      int s = rs[k], q2 = rq[k];
#pragma unroll
      for (int d=32; d>0; d>>=1){ s += __shfl_down(s,d); q2 += __shfl_down(q2,d); }
      if (lane==0){
        part2[blockIdx.x*100 + o*2]     = s;
        part2[blockIdx.x*100 + o*2 + 1] = q2;
      }
    }
  }
}

// one block per channel; sums nchunk partial entries (layout [chunk][100])
__global__ __launch_bounds__(256) void k_reduce2(const int* __restrict__ part2,
        int nchunk, const float* __restrict__ alpha2, const float* __restrict__ g,
        const float* __restrict__ b, float* __restrict__ s2t2){
  __shared__ long long rs[256], rq[256];
  int o = blockIdx.x;          // 0..49
  int tid = threadIdx.x;
  long long s=0, q=0;
  for (int i=tid;i<nchunk;i+=256){
    s += part2[i*100 + o*2];
    q += part2[i*100 + o*2 + 1];
  }
  rs[tid]=s; rq[tid]=q;
  __syncthreads();
  for (int d=128; d>0; d>>=1){
    if (tid<d){ rs[tid]+=rs[tid+d]; rq[tid]+=rq[tid+d]; }
    __syncthreads();
  }
  if (tid==0){
    double N = 8192.0*64.0;
    double meanS = (double)rs[0]/N, E2 = (double)rq[0]/N;
    double varS = E2 - meanS*meanS;
    double a = (double)alpha2[o];
    double mean_g = a*meanS, var_g = a*a*varS;
    double r = 1.0/sqrt(var_g + 1e-5);
    double sc = (double)g[o]*r;
    s2t2[o*2]   = (float)(sc*a);                      // applied to integer S
    s2t2[o*2+1] = (float)((double)b[o] - mean_g*sc);
  }
}

// ---------------------------------------------------------------------------
// Stage 3 FUSED: mask2 built in-block from S16 (ballot pool), fc1 popcount,
// S3 store + per-block stats partials. 8 img/block, grid 1024.
// ---------------------------------------------------------------------------
__global__ __launch_bounds__(256) void k_fc1f(const short* __restrict__ S16,
    const float* __restrict__ s2t2, const unsigned* __restrict__ wpos,
    const unsigned* __restrict__ wneg, const int* __restrict__ flags3,
    short* __restrict__ S3, int* __restrict__ part3){
  __shared__ float st[100];
  __shared__ unsigned m2s[8*25];
  __shared__ short s3s[8*500];
  int tid = threadIdx.x;
  if (tid < 100) st[tid] = s2t2[tid];
  if (tid < 200) m2s[tid] = 0u;
  __syncthreads();
  int lane = tid & 63, wid = tid >> 6;
  size_t base = (size_t)blockIdx.x * 8;
  // phase A: bin2 threshold + 2x2 ballot-pool; wave owns images wid, wid+4
#pragma unroll
  for (int ii=0; ii<2; ++ii){
    int img = wid + 4*ii;
    size_t gimg = base + img;
#pragma unroll 1
    for (int o=0;o<50;o++){
      int S = S16[(gimg*50 + o)*64 + lane];
      bool cond = fmaf((float)S, st[o*2], st[o*2+1]) > 0.f;
      unsigned long long bal = __ballot(cond);
      unsigned long long t4 = bal | (bal>>1) | (bal>>8) | (bal>>9);
      bool pb = (lane < 16) && ((t4 >> (16*(lane>>2) + 2*(lane&3))) & 1ull);
      unsigned long long bal2 = __ballot(pb);
      if (lane==0)
        m2s[img*25 + (o>>1)] |= ((unsigned)(bal2 & 0xFFFFull)) << (16*(o&1));
    }
  }
  __syncthreads();
  // phase B: fc1 popcount
  int f = 0;
  for (int i=0;i<49;i++) f |= flags3[i];
  int bl = tid & 7;
  int jg = tid >> 3;   // 32 groups
  const unsigned* mrow = &m2s[bl*25];
  if (f == 0){
    int pbase = 0;
#pragma unroll
    for (int w=0;w<25;w++) pbase += __popc(mrow[w]);
#pragma unroll 1
    for (int j=jg; j<500; j+=32){
      const unsigned* n = &wneg[j*25];
      int Sn = 0;
#pragma unroll
      for (int w=0;w<25;w++) Sn += __popc(mrow[w] & n[w]);
      s3s[bl*500 + j] = (short)(pbase - 2*Sn);
    }
  } else {
#pragma unroll 1
    for (int j=jg; j<500; j+=32){
      const unsigned* p = &wpos[j*25];
      const unsigned* n = &wneg[j*25];
      int S = 0;
#pragma unroll
      for (int w=0;w<25;w++){
        unsigned m = mrow[w];
        S += __popc(m & p[w]) - __popc(m & n[w]);
      }
      s3s[bl*500 + j] = (short)S;
    }
  }
  __syncthreads();
  // phase C: S3 store + per-block per-feature partial stats
  for (int i=tid;i<8*500;i+=256) S3[base*500 + i] = s3s[i];
  for (int j=tid;j<500;j+=256){
    int s=0, q=0;
#pragma unroll
    for (int im=0;im<8;im++){
      int v = s3s[im*500 + j];
      s += v; q += v*v;
    }
    part3[blockIdx.x*1000 + j*2]     = s;
    part3[blockIdx.x*1000 + j*2 + 1] = q;
  }
}

// fallback: bin2_lite + old fc1 + stats3 chain (kept for !useMM/!useS16)
#define BIN2_POOL_BODY                                                        \
    unsigned long long bal = __ballot(cond);                                  \
    unsigned long long t4 = bal | (bal>>1) | (bal>>8) | (bal>>9);             \
    bool pb = (lane < 16) && ((t4 >> (16*(lane>>2) + 2*(lane&3))) & 1ull);    \
    unsigned long long bal2 = __ballot(pb);                                   \
    if (lane==0){                                                             \
      unsigned pooled16 = (unsigned)(bal2 & 0xFFFFull);                       \
      lw[wid*25 + (o>>1)] |= pooled16 << (16*(o&1));                          \
    }

__global__ __launch_bounds__(256) void k_bin2_lite(const short* __restrict__ S16,
    const float* __restrict__ s2t2, unsigned* __restrict__ mask2){
  __shared__ float st[100];
  __shared__ unsigned lw[100];
  int tid = threadIdx.x;
  if (tid < 100){ st[tid] = s2t2[tid]; lw[tid] = 0u; }
  __syncthreads();
  int lane = tid & 63, wid = tid >> 6;
  size_t img = (size_t)blockIdx.x*4 + wid;
#pragma unroll 1
  for (int o=0;o<50;o++){
    int S = S16[(img*50 + o)*64 + lane];
    bool cond = fmaf((float)S, st[o*2], st[o*2+1]) > 0.f;
    BIN2_POOL_BODY
  }
  __syncthreads();
  if (tid < 100) mask2[blockIdx.x*100 + tid] = lw[tid];
}

__global__ __launch_bounds__(256) void k_fc1(const unsigned* __restrict__ mask2,
    const unsigned* __restrict__ wpos, const unsigned* __restrict__ wneg,
    const int* __restrict__ flags3, short* __restrict__ S3){
  __shared__ unsigned m2s[8*25];
  __shared__ short s3s[8*500];
  int tid = threadIdx.x;
  size_t base = (size_t)blockIdx.x * 8;
  for (int i=tid;i<200;i+=256) m2s[i] = mask2[base*25 + i];
  __syncthreads();
  int f = 0;
  for (int i=0;i<49;i++) f |= flags3[i];
  int bl = tid & 7;
  int jg = tid >> 3;
  const unsigned* mrow = &m2s[bl*25];
  if (f == 0){
    int pbase = 0;
#pragma unroll
    for (int w=0;w<25;w++) pbase += __popc(mrow[w]);
#pragma unroll 1
    for (int j=jg; j<500; j+=32){
      const unsigned* n = &wneg[j*25];
      int Sn = 0;
#pragma unroll
      for (int w=0;w<25;w++) Sn += __popc(mrow[w] & n[w]);
      s3s[bl*500 + j] = (short)(pbase - 2*Sn);
    }
  } else {
#pragma unroll 1
    for (int j=jg; j<500; j+=32){
      const unsigned* p = &wpos[j*25];
      const unsigned* n = &wneg[j*25];
      int S = 0;
#pragma unroll
      for (int w=0;w<25;w++){
        unsigned m = mrow[w];
        S += __popc(m & p[w]) - __popc(m & n[w]);
      }
      s3s[bl*500 + j] = (short)S;
    }
  }
  __syncthreads();
  for (int i=tid;i<8*500;i+=256) S3[base*500 + i] = s3s[i];
}

__global__ __launch_bounds__(256) void k_stats3(const short* __restrict__ S3,
                                                int* __restrict__ part3){
  int tid = threadIdx.x;
  const short* p = &S3[(size_t)blockIdx.x * 64 * 500];
  int s0=0,q0=0,s1=0,q1=0;
  for (int b=0;b<64;b++){
    int v0 = p[b*500 + tid];
    s0 += v0; q0 += v0*v0;
    if (tid < 244){
      int v1 = p[b*500 + tid + 256];
      s1 += v1; q1 += v1*v1;
    }
  }
  part3[blockIdx.x*1000 + tid*2]     = s0;
  part3[blockIdx.x*1000 + tid*2 + 1] = q0;
  if (tid < 244){
    part3[blockIdx.x*1000 + (tid+256)*2]     = s1;
    part3[blockIdx.x*1000 + (tid+256)*2 + 1] = q1;
  }
}

// one block per feature j; sums nchunk partials
__global__ __launch_bounds__(256) void k_reduce3(const int* __restrict__ part3,
        int nchunk, const float* __restrict__ alpha3, const float* __restrict__ g,
        const float* __restrict__ b, float* __restrict__ s3t3){
  __shared__ long long rs[256], rq[256];
  int j = blockIdx.x;          // 0..499
  int tid = threadIdx.x;
  long long s=0, q=0;
  for (int i=tid;i<nchunk;i+=256){
    s += part3[i*1000 + j*2];
    q += part3[i*1000 + j*2 + 1];
  }
  rs[tid]=s; rq[tid]=q;
  __syncthreads();
  for (int d=128; d>0; d>>=1){
    if (tid<d){ rs[tid]+=rs[tid+d]; rq[tid]+=rq[tid+d]; }
    __syncthreads();
  }
  if (tid==0){
    double N = 8192.0;
    double meanS = (double)rs[0]/N, E2 = (double)rq[0]/N;
    double varS = E2 - meanS*meanS;
    double a = (double)alpha3[j];
    double mean_u = a*meanS, var_u = a*a*varS;
    double r = 1.0/sqrt(var_u + 1e-5);
    double sc = (double)g[j]*r;
    s3t3[j*2]   = (float)(sc*a);
    s3t3[j*2+1] = (float)((double)b[j] - mean_u*sc);
  }
}

// h3 = relu(s3*S3 + t3); out = h3 @ fc2_w^T + fc2_b
__global__ __launch_bounds__(256) void k_final(const short* __restrict__ S3,
    const float* __restrict__ s3t3, const float* __restrict__ fc2w,
    const float* __restrict__ fc2b, float* __restrict__ out){
  __shared__ float w[5000];
  __shared__ float st[1000];
  __shared__ float bias[10];
  int tid = threadIdx.x;
  for (int i=tid;i<5000;i+=256) w[i] = fc2w[i];
  for (int i=tid;i<1000;i+=256) st[i] = s3t3[i];
  if (tid<10) bias[tid] = fc2b[tid];
  __syncthreads();
  int sub = tid & 7;
  int li  = tid >> 3;
  size_t b = (size_t)blockIdx.x*32 + li;
  const short* sp = &S3[b*500];
  float acc[10];
#pragma unroll
  for (int m=0;m<10;m++) acc[m] = 0.f;
#pragma unroll 1
  for (int j=sub; j<500; j+=8){
    float h = fmaf((float)sp[j], st[j*2], st[j*2+1]);
    h = fmaxf(h, 0.f);
#pragma unroll
    for (int m=0;m<10;m++) acc[m] = fmaf(h, w[m*500+j], acc[m]);
  }
#pragma unroll
  for (int m=0;m<10;m++){
    float v = acc[m];
    v += __shfl_xor(v, 1);
    v += __shfl_xor(v, 2);
    v += __shfl_xor(v, 4);
    acc[m] = v;
  }
  if (sub == 0){
#pragma unroll
    for (int m=0;m<10;m++) out[b*10 + m] = acc[m] + bias[m];
  }
}

// ---------------------------------------------------------------------------
extern "C" void kernel_launch(void* const* d_in, const int* in_sizes, int n_in,
                              void* d_out, int out_size, void* d_ws, size_t ws_size,
                              hipStream_t stream){
  const float* x    = (const float*)d_in[0];
  const float* w1   = (const float*)d_in[1];
  const float* bn1g = (const float*)d_in[2];
  const float* bn1b = (const float*)d_in[3];
  const float* w2   = (const float*)d_in[4];
  const float* bn2g = (const float*)d_in[5];
  const float* bn2b = (const float*)d_in[6];
  const float* w3   = (const float*)d_in[7];
  const float* bn3g = (const float*)d_in[8];
  const float* bn3b = (const float*)d_in[9];
  const float* w4   = (const float*)d_in[10];
  const float* b4   = (const float*)d_in[11];
  float* out = (float*)d_out;
  (void)in_sizes; (void)n_in; (void)out_size;

  char* wsb = (char*)d_ws;
  size_t off = 0;
  auto alloc = [&](size_t n){ size_t o = off; off = (off + n + 255) & ~(size_t)255; return o; };
  float*    s1t1   = (float*)(wsb + alloc(40*sizeof(float)));
  float*    s2t2   = (float*)(wsb + alloc(100*sizeof(float)));
  float*    s3t3   = (float*)(wsb + alloc(1000*sizeof(float)));
  float*    alpha2 = (float*)(wsb + alloc(50*sizeof(float)));
  float*    alpha3 = (float*)(wsb + alloc(500*sizeof(float)));
  int*      flags2 = (int*)(wsb + alloc(5*4));
  int*      flags3 = (int*)(wsb + alloc(49*4));
  unsigned* wpos2  = (unsigned*)(wsb + alloc(1250*4));
  unsigned* wneg2  = (unsigned*)(wsb + alloc(1250*4));
  unsigned* wpos3  = (unsigned*)(wsb + alloc(12500*4));
  unsigned* wneg3  = (unsigned*)(wsb + alloc(12500*4));
  float*    part1  = (float*)(wsb + alloc(1024*40*4));
  int*      part2  = (int*)(wsb + alloc(2048*100*4));
  int*      part3  = (int*)(wsb + alloc(1024*1000*4));
  unsigned* mask1  = (unsigned*)(wsb + alloc((size_t)BATCH*144*4));
  unsigned* mask2  = (unsigned*)(wsb + alloc((size_t)BATCH*25*4));
  short*    S3     = (short*)(wsb + alloc((size_t)BATCH*500*2));
  // optional staging buffers (runtime-gated on ws_size)
  short*    S16    = (short*)(wsb + alloc((size_t)BATCH*50*64*2));
  bool useS16 = (ws_size >= off);
  float2*   c1ext  = (float2*)(wsb + alloc((size_t)10*NJOB*8));
  bool useMM  = (ws_size >= off);

  hipLaunchKernelGGL(k_pack, dim3(54), dim3(256), 0, stream,
                     w2, w3, wpos2, wneg2, alpha2, wpos3, wneg3, alpha3, flags2, flags3);
  if (useMM)
    hipLaunchKernelGGL(HIP_KERNEL_NAME(k_conv1_stats<true>),  dim3(1024), dim3(256), 0, stream, x, w1, bn1g, part1, c1ext);
  else
    hipLaunchKernelGGL(HIP_KERNEL_NAME(k_conv1_stats<false>), dim3(1024), dim3(256), 0, stream, x, w1, bn1g, part1, c1ext);
  hipLaunchKernelGGL(k_reduce1,      dim3(20),    dim3(256), 0, stream, part1, bn1g, bn1b, s1t1);

  if (useMM && useS16){
    // fused fast path
    hipLaunchKernelGGL(k_conv2f,     dim3(2048),  dim3(256), 0, stream, c1ext, s1t1, wpos2, wneg2, flags2, S16);
    hipLaunchKernelGGL(k_stats2,     dim3(256),   dim3(256), 0, stream, S16, part2);
    hipLaunchKernelGGL(k_reduce2,    dim3(50),    dim3(256), 0, stream, part2, 256, alpha2, bn2g, bn2b, s2t2);
    hipLaunchKernelGGL(k_fc1f,       dim3(1024),  dim3(256), 0, stream, S16, s2t2, wpos3, wneg3, flags3, S3, part3);
    hipLaunchKernelGGL(k_reduce3,    dim3(500),   dim3(256), 0, stream, part3, 1024, alpha3, bn3g, bn3b, s3t3);
  } else {
    // fallback: recompute conv1 bin, legacy conv2, separate bin2/fc1/stats3
    hipLaunchKernelGGL(k_conv1_bin,  dim3(1024),  dim3(256), 0, stream, x, w1, s1t1, mask1);
    hipLaunchKernelGGL(k_conv2,      dim3(2048),  dim3(256), 0, stream, mask1, wpos2, wneg2, flags2, S16);
    hipLaunchKernelGGL(k_stats2,     dim3(256),   dim3(256), 0, stream, S16, part2);
    hipLaunchKernelGGL(k_reduce2,    dim3(50),    dim3(256), 0, stream, part2, 256, alpha2, bn2g, bn2b, s2t2);
    hipLaunchKernelGGL(k_bin2_lite,  dim3(2048),  dim3(256), 0, stream, S16, s2t2, mask2);
    hipLaunchKernelGGL(k_fc1,        dim3(1024),  dim3(256), 0, stream, mask2, wpos3, wneg3, flags3, S3);
    hipLaunchKernelGGL(k_stats3,     dim3(128),   dim3(256), 0, stream, S3, part3);
    hipLaunchKernelGGL(k_reduce3,    dim3(500),   dim3(256), 0, stream, part3, 128, alpha3, bn3g, bn3b, s3t3);
  }
  hipLaunchKernelGGL(k_final,        dim3(256),   dim3(256), 0, stream, S3, s3t3, w4, b4, out);
}

// Round 16
// 314.961 us; speedup vs baseline: 1.1632x; 1.1163x over previous
//
#include <hip/hip_runtime.h>
#include <stdint.h>

#define BATCH 8192
#define NJOB  1179648   // 8192*144

// ---------------------------------------------------------------------------
// Stage 0 (merged): pack binarized weights + alphas + per-block zero flags.
// ---------------------------------------------------------------------------
__global__ __launch_bounds__(256) void k_pack(const float* __restrict__ w2,
    const float* __restrict__ w3, unsigned* __restrict__ wpos2,
    unsigned* __restrict__ wneg2, float* __restrict__ alpha2,
    unsigned* __restrict__ wpos3, unsigned* __restrict__ wneg3,
    float* __restrict__ alpha3, int* __restrict__ flags2, int* __restrict__ flags3){
  __shared__ int zf;
  int tid = threadIdx.x;
  if (tid == 0) zf = 0;
  __syncthreads();
  if (blockIdx.x < 5){
    int t = blockIdx.x*256 + tid;
    int had0 = 0;
    if (t < 1250){                     // t = o*25 + k
      int o = t/25, k = t%25;
      unsigned p=0, n=0;
      for (int i=0;i<20;i++){
        float v = w2[(o*20+i)*25 + k];
        if (v > 0.f) p |= 1u<<i;
        else if (v < 0.f) n |= 1u<<i;
        else had0 = 1;
      }
      wpos2[t] = p; wneg2[t] = n;
    }
    if (t < 50){
      float s = 0.f;
      for (int i=0;i<500;i++) s += fabsf(w2[t*500+i]);
      alpha2[t] = s / 500.f;
    }
    if (had0) atomicOr(&zf, 1);
    __syncthreads();
    if (tid == 0) flags2[blockIdx.x] = zf;
  } else {
    int t = (blockIdx.x-5)*256 + tid;
    int had0 = 0;
    if (t < 12500){                    // t = j*25 + w
      int j = t/25, w = t%25;
      unsigned p=0, n=0;
      for (int bb=0;bb<32;bb++){
        float v = w3[j*800 + w*32 + bb];
        if (v > 0.f) p |= 1u<<bb;
        else if (v < 0.f) n |= 1u<<bb;
        else had0 = 1;
      }
      wpos3[t] = p; wneg3[t] = n;
    }
    if (t < 500){
      float s = 0.f;
      for (int i=0;i<800;i++) s += fabsf(w3[t*800+i]);
      alpha3[t] = s / 800.f;
    }
    if (had0) atomicOr(&zf, 1);
    __syncthreads();
    if (tid == 0) flags3[blockIdx.x-5] = zf;
  }
}

// ---------------------------------------------------------------------------
// Stage 1: conv1 (fp32). 8 images/block, grid 1024. Channel-pair outer loop,
// row-streaming inner conv (round-11 form: best measured, 86us).
// ---------------------------------------------------------------------------

#define CONV1_ROWS(IPTR)                                                      \
  float vA0=0.f,vA1=0.f,vA2=0.f,vA3=0.f;                                      \
  float vB0=0.f,vB1=0.f,vB2=0.f,vB3=0.f;                                      \
  _Pragma("unroll")                                                           \
  for (int r=0;r<6;r++){                                                      \
    const float2* rp = (const float2*)((IPTR) + r*28);                        \
    float2 p0 = rp[0], p1 = rp[1], p2 = rp[2];                                \
    float row0=p0.x, row1=p0.y, row2=p1.x, row3=p1.y, row4=p2.x, row5=p2.y;   \
    if (r<5){                                                                 \
      _Pragma("unroll")                                                       \
      for (int kx=0;kx<5;kx++){                                               \
        float e0 = (kx==0?row0:kx==1?row1:kx==2?row2:kx==3?row3:row4);        \
        float e1 = (kx==0?row1:kx==1?row2:kx==2?row3:kx==3?row4:row5);        \
        float w = wa[r*5+kx], u = wb[r*5+kx];                                 \
        vA0=fmaf(e0,w,vA0); vA1=fmaf(e1,w,vA1);                               \
        vB0=fmaf(e0,u,vB0); vB1=fmaf(e1,u,vB1);                               \
      }                                                                       \
    }                                                                         \
    if (r>0){                                                                 \
      _Pragma("unroll")                                                       \
      for (int kx=0;kx<5;kx++){                                               \
        float e0 = (kx==0?row0:kx==1?row1:kx==2?row2:kx==3?row3:row4);        \
        float e1 = (kx==0?row1:kx==1?row2:kx==2?row3:kx==3?row4:row5);        \
        float w = wa[(r-1)*5+kx], u = wb[(r-1)*5+kx];                         \
        vA2=fmaf(e0,w,vA2); vA3=fmaf(e1,w,vA3);                               \
        vB2=fmaf(e0,u,vB2); vB3=fmaf(e1,u,vB3);                               \
      }                                                                       \
    }                                                                         \
  }

template<bool STORE_MM>
__global__ __launch_bounds__(256) void k_conv1_stats(const float* __restrict__ x,
        const float* __restrict__ w1, const float* __restrict__ g1,
        float* __restrict__ part1, float2* __restrict__ c1ext){
  __shared__ float img[8*784];
  __shared__ float wsh[500];
  __shared__ float gsh[20];
  __shared__ float red[4][40];
  int tid = threadIdx.x;
  size_t base = (size_t)blockIdx.x * 8;
  const float4* xv = (const float4*)(x + base*784);
  float4* iv = (float4*)img;
  for (int i=tid;i<1568;i+=256) iv[i] = xv[i];
  for (int i=tid;i<500;i+=256)  wsh[i] = w1[i];
  if (tid < 20) gsh[tid] = g1[tid];
  __syncthreads();
  int lane = tid & 63, wid = tid >> 6;
#pragma unroll 1
  for (int cg=0; cg<10; ++cg){
    float wa[25], wb[25];
#pragma unroll
    for (int k=0;k<25;k++){ wa[k]=wsh[(2*cg)*25+k]; wb[k]=wsh[(2*cg+1)*25+k]; }
    float gA = gsh[2*cg], gB = gsh[2*cg+1];
    float sa=0.f, qa=0.f, sb=0.f, qb=0.f;
#pragma unroll 1
    for (int job=tid; job<8*144; job+=256){
      int li = job/144, pp = job%144;
      int py = pp/12, px = pp%12;
      const float* ip = &img[li*784 + py*56 + px*2];
      CONV1_ROWS(ip)
      sa += (vA0+vA1)+(vA2+vA3);
      qa = fmaf(vA0,vA0, fmaf(vA1,vA1, fmaf(vA2,vA2, fmaf(vA3,vA3, qa))));
      sb += (vB0+vB1)+(vB2+vB3);
      qb = fmaf(vB0,vB0, fmaf(vB1,vB1, fmaf(vB2,vB2, fmaf(vB3,vB3, qb))));
      if (STORE_MM){
        float mxA = fmaxf(fmaxf(vA0,vA1),fmaxf(vA2,vA3));
        float mnA = fminf(fminf(vA0,vA1),fminf(vA2,vA3));
        float mxB = fmaxf(fmaxf(vB0,vB1),fmaxf(vB2,vB3));
        float mnB = fminf(fminf(vB0,vB1),fminf(vB2,vB3));
        float eA = (gA > 0.f) ? mxA : mnA;
        float eB = (gB > 0.f) ? mxB : mnB;
        c1ext[(size_t)cg*NJOB + (base+li)*144 + pp] = make_float2(eA,eB);
      }
    }
#pragma unroll
    for (int d=32; d>0; d>>=1){
      sa += __shfl_down(sa,d); qa += __shfl_down(qa,d);
      sb += __shfl_down(sb,d); qb += __shfl_down(qb,d);
    }
    if (lane==0){
      red[wid][(2*cg)*2]   = sa; red[wid][(2*cg)*2+1]   = qa;
      red[wid][(2*cg+1)*2] = sb; red[wid][(2*cg+1)*2+1] = qb;
    }
  }
  __syncthreads();
  if (tid < 40)
    part1[blockIdx.x*40 + tid] = red[0][tid]+red[1][tid]+red[2][tid]+red[3][tid];
}

// one block per channel; 256 threads; deterministic fixed-pairing tree
__global__ __launch_bounds__(256) void k_reduce1(const float* __restrict__ part1,
        const float* __restrict__ g, const float* __restrict__ b,
        float* __restrict__ s1t1){
  __shared__ double rs[256], rq[256];
  int c = blockIdx.x;          // 0..19
  int tid = threadIdx.x;
  double s=0.0, q=0.0;
  for (int i=tid;i<1024;i+=256){
    s += (double)part1[i*40 + c*2];
    q += (double)part1[i*40 + c*2 + 1];
  }
  rs[tid]=s; rq[tid]=q;
  __syncthreads();
  for (int d=128; d>0; d>>=1){
    if (tid<d){ rs[tid]+=rs[tid+d]; rq[tid]+=rq[tid+d]; }
    __syncthreads();
  }
  if (tid==0){
    double N = 8192.0*576.0;
    double mean = rs[0]/N, var = rq[0]/N - mean*mean;
    double r = 1.0/sqrt(var + 1e-5);
    double sc = (double)g[c]*r;
    s1t1[c*2]   = (float)sc;
    s1t1[c*2+1] = (float)((double)b[c] - mean*sc);
  }
}

// fallback pass B (recompute): conv1 + threshold + OR-pool, per-job LDS word
__global__ __launch_bounds__(256) void k_conv1_bin(const float* __restrict__ x,
        const float* __restrict__ w1, const float* __restrict__ s1t1,
        unsigned* __restrict__ mask1){
  __shared__ float img[8*784];
  __shared__ float wsh[500];
  __shared__ float st[40];
  __shared__ unsigned lw[8*144];
  int tid = threadIdx.x;
  size_t base = (size_t)blockIdx.x * 8;
  const float4* xv = (const float4*)(x + base*784);
  float4* iv = (float4*)img;
  for (int i=tid;i<1568;i+=256) iv[i] = xv[i];
  for (int i=tid;i<500;i+=256)  wsh[i] = w1[i];
  for (int i=tid;i<8*144;i+=256) lw[i] = 0u;
  if (tid < 40) st[tid] = s1t1[tid];
  __syncthreads();
#pragma unroll 1
  for (int cg=0; cg<10; ++cg){
    float wa[25], wb[25];
#pragma unroll
    for (int k=0;k<25;k++){ wa[k]=wsh[(2*cg)*25+k]; wb[k]=wsh[(2*cg+1)*25+k]; }
    float sA = st[(2*cg)*2],   tA = st[(2*cg)*2+1];
    float sB = st[(2*cg+1)*2], tB = st[(2*cg+1)*2+1];
#pragma unroll 1
    for (int job=tid; job<8*144; job+=256){
      int li = job/144, pp = job%144;
      int py = pp/12, px = pp%12;
      const float* ip = &img[li*784 + py*56 + px*2];
      CONV1_ROWS(ip)
      unsigned bA = (fmaf(vA0,sA,tA) > 0.f) || (fmaf(vA1,sA,tA) > 0.f) ||
                    (fmaf(vA2,sA,tA) > 0.f) || (fmaf(vA3,sA,tA) > 0.f);
      unsigned bB = (fmaf(vB0,sB,tB) > 0.f) || (fmaf(vB1,sB,tB) > 0.f) ||
                    (fmaf(vB2,sB,tB) > 0.f) || (fmaf(vB3,sB,tB) > 0.f);
      lw[job] |= (bA << (2*cg)) | (bB << (2*cg+1));
    }
  }
  __syncthreads();
  for (int i=tid;i<8*144;i+=256){
    int li = i/144, pp = i%144;
    mask1[(base+li)*144 + pp] = lw[i];
  }
}

// ---------------------------------------------------------------------------
// Stage 2 FUSED: mask1 computed in-block from c1ext, then popcount -> S16.
// ---------------------------------------------------------------------------
__global__ __launch_bounds__(256) void k_conv2f(const float2* __restrict__ c1ext,
    const float* __restrict__ s1t1, const unsigned* __restrict__ wpos,
    const unsigned* __restrict__ wneg, const int* __restrict__ flags2,
    short* __restrict__ S16){
  __shared__ unsigned m1[4*144];
  __shared__ float st[40];
  __shared__ __align__(16) unsigned wp[1400], wn[1400];   // [50][28] zero-padded
  int tid = threadIdx.x;
  size_t base = (size_t)blockIdx.x * 4;
  bool slow = (flags2[0]|flags2[1]|flags2[2]|flags2[3]|flags2[4]) != 0;
  if (tid < 40) st[tid] = s1t1[tid];
  for (int i=tid;i<1400;i+=256){
    int o = i/28, k = i%28;
    wn[i] = (k<25) ? wneg[o*25+k] : 0u;
    if (slow) wp[i] = (k<25) ? wpos[o*25+k] : 0u;
  }
  __syncthreads();
  // phase A: binarize conv1 output (threshold on stored extreme)
  for (int job=tid; job<4*144; job+=256){
    int li = job/144, pp = job%144;
    unsigned word = 0;
#pragma unroll
    for (int cg=0; cg<10; ++cg){
      float2 v = c1ext[(size_t)cg*NJOB + (base+li)*144 + pp];
      word |= ((fmaf(v.x, st[4*cg+0], st[4*cg+1]) > 0.f) ? 1u : 0u) << (2*cg);
      word |= ((fmaf(v.y, st[4*cg+2], st[4*cg+3]) > 0.f) ? 1u : 0u) << (2*cg+1);
    }
    m1[job] = word;
  }
  __syncthreads();
  // phase B: binary conv2 popcount
  int lane = tid & 63, wid = tid >> 6;
  int y2 = lane >> 3, x2 = lane & 7;
  unsigned mw[25];
  const unsigned* mrow = &m1[wid*144];
#pragma unroll
  for (int ky=0;ky<5;ky++)
#pragma unroll
    for (int kx=0;kx<5;kx++)
      mw[ky*5+kx] = mrow[(y2+ky)*12 + x2+kx];
  short* sp = &S16[((base+wid)*50)*64 + lane];
  if (!slow){
    int pbase = 0;
#pragma unroll
    for (int k=0;k<25;k++) pbase += __popc(mw[k]);
#pragma unroll 1
    for (int o=0;o<50;o++){
      const uint4* n4 = (const uint4*)&wn[o*28];
      int Sn=0;
#pragma unroll
      for (int g=0; g<6; g++){
        uint4 N = n4[g];
        Sn += __popc(mw[4*g]&N.x) + __popc(mw[4*g+1]&N.y)
            + __popc(mw[4*g+2]&N.z) + __popc(mw[4*g+3]&N.w);
      }
      Sn += __popc(mw[24] & wn[o*28+24]);
      sp[o*64] = (short)(pbase - 2*Sn);
    }
  } else {
#pragma unroll 1
    for (int o=0;o<50;o++){
      const uint4* p4 = (const uint4*)&wp[o*28];
      const uint4* n4 = (const uint4*)&wn[o*28];
      int Sp=0, Sn=0;
#pragma unroll
      for (int g=0; g<6; g++){
        uint4 P = p4[g], N = n4[g];
        Sp += __popc(mw[4*g]&P.x) + __popc(mw[4*g+1]&P.y)
            + __popc(mw[4*g+2]&P.z) + __popc(mw[4*g+3]&P.w);
        Sn += __popc(mw[4*g]&N.x) + __popc(mw[4*g+1]&N.y)
            + __popc(mw[4*g+2]&N.z) + __popc(mw[4*g+3]&N.w);
      }
      Sp += __popc(mw[24] & wp[o*28+24]);
      Sn += __popc(mw[24] & wn[o*28+24]);
      sp[o*64] = (short)(Sp - Sn);
    }
  }
}

// legacy conv2 from mask1 (fallback when !useMM): S16 only
__global__ __launch_bounds__(256) void k_conv2(const unsigned* __restrict__ mask1,
    const unsigned* __restrict__ wpos, const unsigned* __restrict__ wneg,
    const int* __restrict__ flags2, short* __restrict__ S16){
  __shared__ unsigned m1[4*144];
  __shared__ __align__(16) unsigned wp[1400], wn[1400];
  int tid = threadIdx.x;
  size_t base = (size_t)blockIdx.x * 4;
  bool slow = (flags2[0]|flags2[1]|flags2[2]|flags2[3]|flags2[4]) != 0;
  for (int i=tid;i<4*144;i+=256) m1[i] = mask1[base*144 + i];
  for (int i=tid;i<1400;i+=256){
    int o = i/28, k = i%28;
    wn[i] = (k<25) ? wneg[o*25+k] : 0u;
    if (slow) wp[i] = (k<25) ? wpos[o*25+k] : 0u;
  }
  __syncthreads();
  int lane = tid & 63, wid = tid >> 6;
  int y2 = lane >> 3, x2 = lane & 7;
  unsigned mw[25];
  const unsigned* mrow = &m1[wid*144];
#pragma unroll
  for (int ky=0;ky<5;ky++)
#pragma unroll
    for (int kx=0;kx<5;kx++)
      mw[ky*5+kx] = mrow[(y2+ky)*12 + x2+kx];
  short* sp = &S16[((base+wid)*50)*64 + lane];
  if (!slow){
    int pbase = 0;
#pragma unroll
    for (int k=0;k<25;k++) pbase += __popc(mw[k]);
#pragma unroll 1
    for (int o=0;o<50;o++){
      const uint4* n4 = (const uint4*)&wn[o*28];
      int Sn=0;
#pragma unroll
      for (int g=0; g<6; g++){
        uint4 N = n4[g];
        Sn += __popc(mw[4*g]&N.x) + __popc(mw[4*g+1]&N.y)
            + __popc(mw[4*g+2]&N.z) + __popc(mw[4*g+3]&N.w);
      }
      Sn += __popc(mw[24] & wn[o*28+24]);
      sp[o*64] = (short)(pbase - 2*Sn);
    }
  } else {
#pragma unroll 1
    for (int o=0;o<50;o++){
      const uint4* p4 = (const uint4*)&wp[o*28];
      const uint4* n4 = (const uint4*)&wn[o*28];
      int Sp=0, Sn=0;
#pragma unroll
      for (int g=0; g<6; g++){
        uint4 P = p4[g], N = n4[g];
        Sp += __popc(mw[4*g]&P.x) + __popc(mw[4*g+1]&P.y)
            + __popc(mw[4*g+2]&P.z) + __popc(mw[4*g+3]&P.w);
        Sn += __popc(mw[4*g]&N.x) + __popc(mw[4*g+1]&N.y)
            + __popc(mw[4*g+2]&N.z) + __popc(mw[4*g+3]&N.w);
      }
      Sp += __popc(mw[24] & wp[o*28+24]);
      Sn += __popc(mw[24] & wn[o*28+24]);
      sp[o*64] = (short)(Sp - Sn);
    }
  }
}

// streaming stats over S16: grid 256 blocks x 32 images; 128B-coalesced.
__global__ __launch_bounds__(256) void k_stats2(const short* __restrict__ S16,
        int* __restrict__ part2){
  int tid = threadIdx.x;
  int lane = tid & 63, wid = tid >> 6;
  const short* p = S16 + (size_t)blockIdx.x * 32 * 3200;
  int rs[13], rq[13];
#pragma unroll
  for (int k=0;k<13;k++){ rs[k]=0; rq[k]=0; }
#pragma unroll 1
  for (int im=0; im<32; ++im){
    const short* q = p + im*3200 + tid;
#pragma unroll
    for (int k=0;k<13;k++){
      if (wid + 4*k < 50){
        int v = q[256*k];
        rs[k] += v; rq[k] += v*v;
      }
    }
  }
#pragma unroll
  for (int k=0;k<13;k++){
    int o = wid + 4*k;
    if (o < 50){
      int s = rs[k], q2 = rq[k];
#pragma unroll
      for (int d=32; d>0; d>>=1){ s += __shfl_down(s,d); q2 += __shfl_down(q2,d); }
      if (lane==0){
        part2[blockIdx.x*100 + o*2]     = s;
        part2[blockIdx.x*100 + o*2 + 1] = q2;
      }
    }
  }
}

// one block per channel; sums nchunk partial entries (layout [chunk][100])
__global__ __launch_bounds__(256) void k_reduce2(const int* __restrict__ part2,
        int nchunk, const float* __restrict__ alpha2, const float* __restrict__ g,
        const float* __restrict__ b, float* __restrict__ s2t2){
  __shared__ long long rs[256], rq[256];
  int o = blockIdx.x;          // 0..49
  int tid = threadIdx.x;
  long long s=0, q=0;
  for (int i=tid;i<nchunk;i+=256){
    s += part2[i*100 + o*2];
    q += part2[i*100 + o*2 + 1];
  }
  rs[tid]=s; rq[tid]=q;
  __syncthreads();
  for (int d=128; d>0; d>>=1){
    if (tid<d){ rs[tid]+=rs[tid+d]; rq[tid]+=rq[tid+d]; }
    __syncthreads();
  }
  if (tid==0){
    double N = 8192.0*64.0;
    double meanS = (double)rs[0]/N, E2 = (double)rq[0]/N;
    double varS = E2 - meanS*meanS;
    double a = (double)alpha2[o];
    double mean_g = a*meanS, var_g = a*a*varS;
    double r = 1.0/sqrt(var_g + 1e-5);
    double sc = (double)g[o]*r;
    s2t2[o*2]   = (float)(sc*a);                      // applied to integer S
    s2t2[o*2+1] = (float)((double)b[o] - mean_g*sc);
  }
}

#define BIN2_POOL_BODY                                                        \
    unsigned long long bal = __ballot(cond);                                  \
    unsigned long long t4 = bal | (bal>>1) | (bal>>8) | (bal>>9);             \
    bool pb = (lane < 16) && ((t4 >> (16*(lane>>2) + 2*(lane&3))) & 1ull);    \
    unsigned long long bal2 = __ballot(pb);                                   \
    if (lane==0){                                                             \
      unsigned pooled16 = (unsigned)(bal2 & 0xFFFFull);                       \
      lw[wid*25 + (o>>1)] |= pooled16 << (16*(o&1));                          \
    }

// bin2: read S16, threshold, ballot-pool, pack. 4 img/block, grid 2048.
__global__ __launch_bounds__(256) void k_bin2_lite(const short* __restrict__ S16,
    const float* __restrict__ s2t2, unsigned* __restrict__ mask2){
  __shared__ float st[100];
  __shared__ unsigned lw[100];
  int tid = threadIdx.x;
  if (tid < 100){ st[tid] = s2t2[tid]; lw[tid] = 0u; }
  __syncthreads();
  int lane = tid & 63, wid = tid >> 6;
  size_t img = (size_t)blockIdx.x*4 + wid;
#pragma unroll 1
  for (int o=0;o<50;o++){
    int S = S16[(img*50 + o)*64 + lane];
    bool cond = fmaf((float)S, st[o*2], st[o*2+1]) > 0.f;
    BIN2_POOL_BODY
  }
  __syncthreads();
  if (tid < 100) mask2[blockIdx.x*100 + tid] = lw[tid];
}

// ---------------------------------------------------------------------------
// Stage 3: binary fc1 (800 -> 500). 8 img/block, grid 1024.
// ---------------------------------------------------------------------------
__global__ __launch_bounds__(256) void k_fc1(const unsigned* __restrict__ mask2,
    const unsigned* __restrict__ wpos, const unsigned* __restrict__ wneg,
    const int* __restrict__ flags3, short* __restrict__ S3){
  __shared__ unsigned m2s[8*25];
  __shared__ short s3s[8*500];
  int tid = threadIdx.x;
  size_t base = (size_t)blockIdx.x * 8;
  for (int i=tid;i<200;i+=256) m2s[i] = mask2[base*25 + i];
  __syncthreads();
  int f = 0;
  for (int i=0;i<49;i++) f |= flags3[i];
  int bl = tid & 7;
  int jg = tid >> 3;
  const unsigned* mrow = &m2s[bl*25];
  if (f == 0){
    int pbase = 0;
#pragma unroll
    for (int w=0;w<25;w++) pbase += __popc(mrow[w]);
#pragma unroll 1
    for (int j=jg; j<500; j+=32){
      const unsigned* n = &wneg[j*25];
      int Sn = 0;
#pragma unroll
      for (int w=0;w<25;w++) Sn += __popc(mrow[w] & n[w]);
      s3s[bl*500 + j] = (short)(pbase - 2*Sn);
    }
  } else {
#pragma unroll 1
    for (int j=jg; j<500; j+=32){
      const unsigned* p = &wpos[j*25];
      const unsigned* n = &wneg[j*25];
      int S = 0;
#pragma unroll
      for (int w=0;w<25;w++){
        unsigned m = mrow[w];
        S += __popc(m & p[w]) - __popc(m & n[w]);
      }
      s3s[bl*500 + j] = (short)S;
    }
  }
  __syncthreads();
  for (int i=tid;i<8*500;i+=256) S3[base*500 + i] = s3s[i];
}

// per-feature batch stats of S3 (int, exact): 64 images/block, 128 blocks
__global__ __launch_bounds__(256) void k_stats3(const short* __restrict__ S3,
                                                int* __restrict__ part3){
  int tid = threadIdx.x;
  const short* p = &S3[(size_t)blockIdx.x * 64 * 500];
  int s0=0,q0=0,s1=0,q1=0;
  for (int b=0;b<64;b++){
    int v0 = p[b*500 + tid];
    s0 += v0; q0 += v0*v0;
    if (tid < 244){
      int v1 = p[b*500 + tid + 256];
      s1 += v1; q1 += v1*v1;
    }
  }
  part3[blockIdx.x*1000 + tid*2]     = s0;
  part3[blockIdx.x*1000 + tid*2 + 1] = q0;
  if (tid < 244){
    part3[blockIdx.x*1000 + (tid+256)*2]     = s1;
    part3[blockIdx.x*1000 + (tid+256)*2 + 1] = q1;
  }
}

// one block per feature j; sums nchunk partials
__global__ __launch_bounds__(256) void k_reduce3(const int* __restrict__ part3,
        int nchunk, const float* __restrict__ alpha3, const float* __restrict__ g,
        const float* __restrict__ b, float* __restrict__ s3t3){
  __shared__ long long rs[256], rq[256];
  int j = blockIdx.x;          // 0..499
  int tid = threadIdx.x;
  long long s=0, q=0;
  for (int i=tid;i<nchunk;i+=256){
    s += part3[i*1000 + j*2];
    q += part3[i*1000 + j*2 + 1];
  }
  rs[tid]=s; rq[tid]=q;
  __syncthreads();
  for (int d=128; d>0; d>>=1){
    if (tid<d){ rs[tid]+=rs[tid+d]; rq[tid]+=rq[tid+d]; }
    __syncthreads();
  }
  if (tid==0){
    double N = 8192.0;
    double meanS = (double)rs[0]/N, E2 = (double)rq[0]/N;
    double varS = E2 - meanS*meanS;
    double a = (double)alpha3[j];
    double mean_u = a*meanS, var_u = a*a*varS;
    double r = 1.0/sqrt(var_u + 1e-5);
    double sc = (double)g[j]*r;
    s3t3[j*2]   = (float)(sc*a);
    s3t3[j*2+1] = (float)((double)b[j] - mean_u*sc);
  }
}

// h3 = relu(s3*S3 + t3); out = h3 @ fc2_w^T + fc2_b
__global__ __launch_bounds__(256) void k_final(const short* __restrict__ S3,
    const float* __restrict__ s3t3, const float* __restrict__ fc2w,
    const float* __restrict__ fc2b, float* __restrict__ out){
  __shared__ float w[5000];
  __shared__ float st[1000];
  __shared__ float bias[10];
  int tid = threadIdx.x;
  for (int i=tid;i<5000;i+=256) w[i] = fc2w[i];
  for (int i=tid;i<1000;i+=256) st[i] = s3t3[i];
  if (tid<10) bias[tid] = fc2b[tid];
  __syncthreads();
  int sub = tid & 7;
  int li  = tid >> 3;
  size_t b = (size_t)blockIdx.x*32 + li;
  const short* sp = &S3[b*500];
  float acc[10];
#pragma unroll
  for (int m=0;m<10;m++) acc[m] = 0.f;
#pragma unroll 1
  for (int j=sub; j<500; j+=8){
    float h = fmaf((float)sp[j], st[j*2], st[j*2+1]);
    h = fmaxf(h, 0.f);
#pragma unroll
    for (int m=0;m<10;m++) acc[m] = fmaf(h, w[m*500+j], acc[m]);
  }
#pragma unroll
  for (int m=0;m<10;m++){
    float v = acc[m];
    v += __shfl_xor(v, 1);
    v += __shfl_xor(v, 2);
    v += __shfl_xor(v, 4);
    acc[m] = v;
  }
  if (sub == 0){
#pragma unroll
    for (int m=0;m<10;m++) out[b*10 + m] = acc[m] + bias[m];
  }
}

// ---------------------------------------------------------------------------
extern "C" void kernel_launch(void* const* d_in, const int* in_sizes, int n_in,
                              void* d_out, int out_size, void* d_ws, size_t ws_size,
                              hipStream_t stream){
  const float* x    = (const float*)d_in[0];
  const float* w1   = (const float*)d_in[1];
  const float* bn1g = (const float*)d_in[2];
  const float* bn1b = (const float*)d_in[3];
  const float* w2   = (const float*)d_in[4];
  const float* bn2g = (const float*)d_in[5];
  const float* bn2b = (const float*)d_in[6];
  const float* w3   = (const float*)d_in[7];
  const float* bn3g = (const float*)d_in[8];
  const float* bn3b = (const float*)d_in[9];
  const float* w4   = (const float*)d_in[10];
  const float* b4   = (const float*)d_in[11];
  float* out = (float*)d_out;
  (void)in_sizes; (void)n_in; (void)out_size;

  char* wsb = (char*)d_ws;
  size_t off = 0;
  auto alloc = [&](size_t n){ size_t o = off; off = (off + n + 255) & ~(size_t)255; return o; };
  float*    s1t1   = (float*)(wsb + alloc(40*sizeof(float)));
  float*    s2t2   = (float*)(wsb + alloc(100*sizeof(float)));
  float*    s3t3   = (float*)(wsb + alloc(1000*sizeof(float)));
  float*    alpha2 = (float*)(wsb + alloc(50*sizeof(float)));
  float*    alpha3 = (float*)(wsb + alloc(500*sizeof(float)));
  int*      flags2 = (int*)(wsb + alloc(5*4));
  int*      flags3 = (int*)(wsb + alloc(49*4));
  unsigned* wpos2  = (unsigned*)(wsb + alloc(1250*4));
  unsigned* wneg2  = (unsigned*)(wsb + alloc(1250*4));
  unsigned* wpos3  = (unsigned*)(wsb + alloc(12500*4));
  unsigned* wneg3  = (unsigned*)(wsb + alloc(12500*4));
  float*    part1  = (float*)(wsb + alloc(1024*40*4));
  int*      part2  = (int*)(wsb + alloc(2048*100*4));
  int*      part3  = (int*)(wsb + alloc(128*1000*4));
  unsigned* mask1  = (unsigned*)(wsb + alloc((size_t)BATCH*144*4));
  unsigned* mask2  = (unsigned*)(wsb + alloc((size_t)BATCH*25*4));
  short*    S3     = (short*)(wsb + alloc((size_t)BATCH*500*2));
  // optional staging buffers (runtime-gated on ws_size)
  short*    S16    = (short*)(wsb + alloc((size_t)BATCH*50*64*2));
  bool useS16 = (ws_size >= off);
  float2*   c1ext  = (float2*)(wsb + alloc((size_t)10*NJOB*8));
  bool useMM  = (ws_size >= off);

  hipLaunchKernelGGL(k_pack, dim3(54), dim3(256), 0, stream,
                     w2, w3, wpos2, wneg2, alpha2, wpos3, wneg3, alpha3, flags2, flags3);
  if (useMM)
    hipLaunchKernelGGL(HIP_KERNEL_NAME(k_conv1_stats<true>),  dim3(1024), dim3(256), 0, stream, x, w1, bn1g, part1, c1ext);
  else
    hipLaunchKernelGGL(HIP_KERNEL_NAME(k_conv1_stats<false>), dim3(1024), dim3(256), 0, stream, x, w1, bn1g, part1, c1ext);
  hipLaunchKernelGGL(k_reduce1,      dim3(20),    dim3(256), 0, stream, part1, bn1g, bn1b, s1t1);

  if (useMM && useS16){
    hipLaunchKernelGGL(k_conv2f,     dim3(2048),  dim3(256), 0, stream, c1ext, s1t1, wpos2, wneg2, flags2, S16);
  } else {
    hipLaunchKernelGGL(k_conv1_bin,  dim3(1024),  dim3(256), 0, stream, x, w1, s1t1, mask1);
    hipLaunchKernelGGL(k_conv2,      dim3(2048),  dim3(256), 0, stream, mask1, wpos2, wneg2, flags2, S16);
  }
  hipLaunchKernelGGL(k_stats2,       dim3(256),   dim3(256), 0, stream, S16, part2);
  hipLaunchKernelGGL(k_reduce2,      dim3(50),    dim3(256), 0, stream, part2, 256, alpha2, bn2g, bn2b, s2t2);
  hipLaunchKernelGGL(k_bin2_lite,    dim3(2048),  dim3(256), 0, stream, S16, s2t2, mask2);
  hipLaunchKernelGGL(k_fc1,          dim3(1024),  dim3(256), 0, stream, mask2, wpos3, wneg3, flags3, S3);
  hipLaunchKernelGGL(k_stats3,       dim3(128),   dim3(256), 0, stream, S3, part3);
  hipLaunchKernelGGL(k_reduce3,      dim3(500),   dim3(256), 0, stream, part3, 128, alpha3, bn3g, bn3b, s3t3);
  hipLaunchKernelGGL(k_final,        dim3(256),   dim3(256), 0, stream, S3, s3t3, w4, b4, out);
}

// Round 17
// 309.344 us; speedup vs baseline: 1.1843x; 1.0182x over previous
//
#include <hip/hip_runtime.h>
#include <stdint.h>

#define BATCH 8192
#define NJOB  1179648   // 8192*144

// ---------------------------------------------------------------------------
// Stage 0 (merged): pack binarized weights + alphas + per-block zero flags.
// ---------------------------------------------------------------------------
__global__ __launch_bounds__(256) void k_pack(const float* __restrict__ w2,
    const float* __restrict__ w3, unsigned* __restrict__ wpos2,
    unsigned* __restrict__ wneg2, float* __restrict__ alpha2,
    unsigned* __restrict__ wpos3, unsigned* __restrict__ wneg3,
    float* __restrict__ alpha3, int* __restrict__ flags2, int* __restrict__ flags3){
  __shared__ int zf;
  int tid = threadIdx.x;
  if (tid == 0) zf = 0;
  __syncthreads();
  if (blockIdx.x < 5){
    int t = blockIdx.x*256 + tid;
    int had0 = 0;
    if (t < 1250){                     // t = o*25 + k
      int o = t/25, k = t%25;
      unsigned p=0, n=0;
      for (int i=0;i<20;i++){
        float v = w2[(o*20+i)*25 + k];
        if (v > 0.f) p |= 1u<<i;
        else if (v < 0.f) n |= 1u<<i;
        else had0 = 1;
      }
      wpos2[t] = p; wneg2[t] = n;
    }
    if (t < 50){
      float s = 0.f;
      for (int i=0;i<500;i++) s += fabsf(w2[t*500+i]);
      alpha2[t] = s / 500.f;
    }
    if (had0) atomicOr(&zf, 1);
    __syncthreads();
    if (tid == 0) flags2[blockIdx.x] = zf;
  } else {
    int t = (blockIdx.x-5)*256 + tid;
    int had0 = 0;
    if (t < 12500){                    // t = j*25 + w
      int j = t/25, w = t%25;
      unsigned p=0, n=0;
      for (int bb=0;bb<32;bb++){
        float v = w3[j*800 + w*32 + bb];
        if (v > 0.f) p |= 1u<<bb;
        else if (v < 0.f) n |= 1u<<bb;
        else had0 = 1;
      }
      wpos3[t] = p; wneg3[t] = n;
    }
    if (t < 500){
      float s = 0.f;
      for (int i=0;i<800;i++) s += fabsf(w3[t*800+i]);
      alpha3[t] = s / 800.f;
    }
    if (had0) atomicOr(&zf, 1);
    __syncthreads();
    if (tid == 0) flags3[blockIdx.x-5] = zf;
  }
}

// ---------------------------------------------------------------------------
// Stage 1: conv1 (fp32). 8 images/block, grid 1024. Channel-pair outer loop,
// row-streaming inner conv. Weights read DIRECTLY FROM GLOBAL with
// wave-uniform addresses -> compiler can use the scalar (s_load/K$) path,
// freeing the DS pipe (r15 showed VGPR=48 => weights were LDS-resident and
// re-read per FMA, the ~38% issue bubble).
// ---------------------------------------------------------------------------

#define CONV1_ROWS(IPTR)                                                      \
  float vA0=0.f,vA1=0.f,vA2=0.f,vA3=0.f;                                      \
  float vB0=0.f,vB1=0.f,vB2=0.f,vB3=0.f;                                      \
  _Pragma("unroll")                                                           \
  for (int r=0;r<6;r++){                                                      \
    const float2* rp = (const float2*)((IPTR) + r*28);                        \
    float2 p0 = rp[0], p1 = rp[1], p2 = rp[2];                                \
    float row0=p0.x, row1=p0.y, row2=p1.x, row3=p1.y, row4=p2.x, row5=p2.y;   \
    if (r<5){                                                                 \
      _Pragma("unroll")                                                       \
      for (int kx=0;kx<5;kx++){                                               \
        float e0 = (kx==0?row0:kx==1?row1:kx==2?row2:kx==3?row3:row4);        \
        float e1 = (kx==0?row1:kx==1?row2:kx==2?row3:kx==3?row4:row5);        \
        float w = wa[r*5+kx], u = wb[r*5+kx];                                 \
        vA0=fmaf(e0,w,vA0); vA1=fmaf(e1,w,vA1);                               \
        vB0=fmaf(e0,u,vB0); vB1=fmaf(e1,u,vB1);                               \
      }                                                                       \
    }                                                                         \
    if (r>0){                                                                 \
      _Pragma("unroll")                                                       \
      for (int kx=0;kx<5;kx++){                                               \
        float e0 = (kx==0?row0:kx==1?row1:kx==2?row2:kx==3?row3:row4);        \
        float e1 = (kx==0?row1:kx==1?row2:kx==2?row3:kx==3?row4:row5);        \
        float w = wa[(r-1)*5+kx], u = wb[(r-1)*5+kx];                         \
        vA2=fmaf(e0,w,vA2); vA3=fmaf(e1,w,vA3);                               \
        vB2=fmaf(e0,u,vB2); vB3=fmaf(e1,u,vB3);                               \
      }                                                                       \
    }                                                                         \
  }

template<bool STORE_MM>
__global__ __launch_bounds__(256) void k_conv1_stats(const float* __restrict__ x,
        const float* __restrict__ w1, const float* __restrict__ g1,
        float* __restrict__ part1, float2* __restrict__ c1ext){
  __shared__ float img[8*784];
  __shared__ float red[4][40];
  int tid = threadIdx.x;
  size_t base = (size_t)blockIdx.x * 8;
  const float4* xv = (const float4*)(x + base*784);
  float4* iv = (float4*)img;
  for (int i=tid;i<1568;i+=256) iv[i] = xv[i];
  __syncthreads();
  int lane = tid & 63, wid = tid >> 6;
#pragma unroll 1
  for (int cg=0; cg<10; ++cg){
    float wa[25], wb[25];
#pragma unroll
    for (int k=0;k<25;k++){ wa[k]=w1[(2*cg)*25+k]; wb[k]=w1[(2*cg+1)*25+k]; }
    float gA = g1[2*cg], gB = g1[2*cg+1];
    float sa=0.f, qa=0.f, sb=0.f, qb=0.f;
#pragma unroll 1
    for (int job=tid; job<8*144; job+=256){
      int li = job/144, pp = job%144;
      int py = pp/12, px = pp%12;
      const float* ip = &img[li*784 + py*56 + px*2];
      CONV1_ROWS(ip)
      sa += (vA0+vA1)+(vA2+vA3);
      qa = fmaf(vA0,vA0, fmaf(vA1,vA1, fmaf(vA2,vA2, fmaf(vA3,vA3, qa))));
      sb += (vB0+vB1)+(vB2+vB3);
      qb = fmaf(vB0,vB0, fmaf(vB1,vB1, fmaf(vB2,vB2, fmaf(vB3,vB3, qb))));
      if (STORE_MM){
        float mxA = fmaxf(fmaxf(vA0,vA1),fmaxf(vA2,vA3));
        float mnA = fminf(fminf(vA0,vA1),fminf(vA2,vA3));
        float mxB = fmaxf(fmaxf(vB0,vB1),fmaxf(vB2,vB3));
        float mnB = fminf(fminf(vB0,vB1),fminf(vB2,vB3));
        float eA = (gA > 0.f) ? mxA : mnA;
        float eB = (gB > 0.f) ? mxB : mnB;
        c1ext[(size_t)cg*NJOB + (base+li)*144 + pp] = make_float2(eA,eB);
      }
    }
#pragma unroll
    for (int d=32; d>0; d>>=1){
      sa += __shfl_down(sa,d); qa += __shfl_down(qa,d);
      sb += __shfl_down(sb,d); qb += __shfl_down(qb,d);
    }
    if (lane==0){
      red[wid][(2*cg)*2]   = sa; red[wid][(2*cg)*2+1]   = qa;
      red[wid][(2*cg+1)*2] = sb; red[wid][(2*cg+1)*2+1] = qb;
    }
  }
  __syncthreads();
  if (tid < 40)
    part1[blockIdx.x*40 + tid] = red[0][tid]+red[1][tid]+red[2][tid]+red[3][tid];
}

// one block per channel; 256 threads; deterministic fixed-pairing tree
__global__ __launch_bounds__(256) void k_reduce1(const float* __restrict__ part1,
        const float* __restrict__ g, const float* __restrict__ b,
        float* __restrict__ s1t1){
  __shared__ double rs[256], rq[256];
  int c = blockIdx.x;          // 0..19
  int tid = threadIdx.x;
  double s=0.0, q=0.0;
  for (int i=tid;i<1024;i+=256){
    s += (double)part1[i*40 + c*2];
    q += (double)part1[i*40 + c*2 + 1];
  }
  rs[tid]=s; rq[tid]=q;
  __syncthreads();
  for (int d=128; d>0; d>>=1){
    if (tid<d){ rs[tid]+=rs[tid+d]; rq[tid]+=rq[tid+d]; }
    __syncthreads();
  }
  if (tid==0){
    double N = 8192.0*576.0;
    double mean = rs[0]/N, var = rq[0]/N - mean*mean;
    double r = 1.0/sqrt(var + 1e-5);
    double sc = (double)g[c]*r;
    s1t1[c*2]   = (float)sc;
    s1t1[c*2+1] = (float)((double)b[c] - mean*sc);
  }
}

// fallback pass B (recompute): conv1 + threshold + OR-pool, per-job LDS word
__global__ __launch_bounds__(256) void k_conv1_bin(const float* __restrict__ x,
        const float* __restrict__ w1, const float* __restrict__ s1t1,
        unsigned* __restrict__ mask1){
  __shared__ float img[8*784];
  __shared__ float st[40];
  __shared__ unsigned lw[8*144];
  int tid = threadIdx.x;
  size_t base = (size_t)blockIdx.x * 8;
  const float4* xv = (const float4*)(x + base*784);
  float4* iv = (float4*)img;
  for (int i=tid;i<1568;i+=256) iv[i] = xv[i];
  for (int i=tid;i<8*144;i+=256) lw[i] = 0u;
  if (tid < 40) st[tid] = s1t1[tid];
  __syncthreads();
#pragma unroll 1
  for (int cg=0; cg<10; ++cg){
    float wa[25], wb[25];
#pragma unroll
    for (int k=0;k<25;k++){ wa[k]=w1[(2*cg)*25+k]; wb[k]=w1[(2*cg+1)*25+k]; }
    float sA = st[(2*cg)*2],   tA = st[(2*cg)*2+1];
    float sB = st[(2*cg+1)*2], tB = st[(2*cg+1)*2+1];
#pragma unroll 1
    for (int job=tid; job<8*144; job+=256){
      int li = job/144, pp = job%144;
      int py = pp/12, px = pp%12;
      const float* ip = &img[li*784 + py*56 + px*2];
      CONV1_ROWS(ip)
      unsigned bA = (fmaf(vA0,sA,tA) > 0.f) || (fmaf(vA1,sA,tA) > 0.f) ||
                    (fmaf(vA2,sA,tA) > 0.f) || (fmaf(vA3,sA,tA) > 0.f);
      unsigned bB = (fmaf(vB0,sB,tB) > 0.f) || (fmaf(vB1,sB,tB) > 0.f) ||
                    (fmaf(vB2,sB,tB) > 0.f) || (fmaf(vB3,sB,tB) > 0.f);
      lw[job] |= (bA << (2*cg)) | (bB << (2*cg+1));
    }
  }
  __syncthreads();
  for (int i=tid;i<8*144;i+=256){
    int li = i/144, pp = i%144;
    mask1[(base+li)*144 + pp] = lw[i];
  }
}

// ---------------------------------------------------------------------------
// Stage 2 FUSED: mask1 computed in-block from c1ext, then popcount -> S16.
// Weight words read directly from global (wave-uniform -> scalar path).
// ---------------------------------------------------------------------------
__global__ __launch_bounds__(256) void k_conv2f(const float2* __restrict__ c1ext,
    const float* __restrict__ s1t1, const unsigned* __restrict__ wpos,
    const unsigned* __restrict__ wneg, const int* __restrict__ flags2,
    short* __restrict__ S16){
  __shared__ unsigned m1[4*144];
  __shared__ float st[40];
  int tid = threadIdx.x;
  size_t base = (size_t)blockIdx.x * 4;
  bool slow = (flags2[0]|flags2[1]|flags2[2]|flags2[3]|flags2[4]) != 0;
  if (tid < 40) st[tid] = s1t1[tid];
  __syncthreads();
  // phase A: binarize conv1 output (threshold on stored extreme)
  for (int job=tid; job<4*144; job+=256){
    int li = job/144, pp = job%144;
    unsigned word = 0;
#pragma unroll
    for (int cg=0; cg<10; ++cg){
      float2 v = c1ext[(size_t)cg*NJOB + (base+li)*144 + pp];
      word |= ((fmaf(v.x, st[4*cg+0], st[4*cg+1]) > 0.f) ? 1u : 0u) << (2*cg);
      word |= ((fmaf(v.y, st[4*cg+2], st[4*cg+3]) > 0.f) ? 1u : 0u) << (2*cg+1);
    }
    m1[job] = word;
  }
  __syncthreads();
  // phase B: binary conv2 popcount (weights via uniform global reads)
  int lane = tid & 63, wid = tid >> 6;
  int y2 = lane >> 3, x2 = lane & 7;
  unsigned mw[25];
  const unsigned* mrow = &m1[wid*144];
#pragma unroll
  for (int ky=0;ky<5;ky++)
#pragma unroll
    for (int kx=0;kx<5;kx++)
      mw[ky*5+kx] = mrow[(y2+ky)*12 + x2+kx];
  short* sp = &S16[((base+wid)*50)*64 + lane];
  if (!slow){
    int pbase = 0;
#pragma unroll
    for (int k=0;k<25;k++) pbase += __popc(mw[k]);
#pragma unroll 1
    for (int o=0;o<50;o++){
      const unsigned* n = &wneg[o*25];
      int Sn=0;
#pragma unroll
      for (int k=0;k<25;k++) Sn += __popc(mw[k] & n[k]);
      sp[o*64] = (short)(pbase - 2*Sn);
    }
  } else {
#pragma unroll 1
    for (int o=0;o<50;o++){
      const unsigned* p = &wpos[o*25];
      const unsigned* n = &wneg[o*25];
      int S=0;
#pragma unroll
      for (int k=0;k<25;k++){
        unsigned m = mw[k];
        S += __popc(m & p[k]) - __popc(m & n[k]);
      }
      sp[o*64] = (short)S;
    }
  }
}

// legacy conv2 from mask1 (fallback when !useMM): S16 only
__global__ __launch_bounds__(256) void k_conv2(const unsigned* __restrict__ mask1,
    const unsigned* __restrict__ wpos, const unsigned* __restrict__ wneg,
    const int* __restrict__ flags2, short* __restrict__ S16){
  __shared__ unsigned m1[4*144];
  int tid = threadIdx.x;
  size_t base = (size_t)blockIdx.x * 4;
  bool slow = (flags2[0]|flags2[1]|flags2[2]|flags2[3]|flags2[4]) != 0;
  for (int i=tid;i<4*144;i+=256) m1[i] = mask1[base*144 + i];
  __syncthreads();
  int lane = tid & 63, wid = tid >> 6;
  int y2 = lane >> 3, x2 = lane & 7;
  unsigned mw[25];
  const unsigned* mrow = &m1[wid*144];
#pragma unroll
  for (int ky=0;ky<5;ky++)
#pragma unroll
    for (int kx=0;kx<5;kx++)
      mw[ky*5+kx] = mrow[(y2+ky)*12 + x2+kx];
  short* sp = &S16[((base+wid)*50)*64 + lane];
  if (!slow){
    int pbase = 0;
#pragma unroll
    for (int k=0;k<25;k++) pbase += __popc(mw[k]);
#pragma unroll 1
    for (int o=0;o<50;o++){
      const unsigned* n = &wneg[o*25];
      int Sn=0;
#pragma unroll
      for (int k=0;k<25;k++) Sn += __popc(mw[k] & n[k]);
      sp[o*64] = (short)(pbase - 2*Sn);
    }
  } else {
#pragma unroll 1
    for (int o=0;o<50;o++){
      const unsigned* p = &wpos[o*25];
      const unsigned* n = &wneg[o*25];
      int S=0;
#pragma unroll
      for (int k=0;k<25;k++){
        unsigned m = mw[k];
        S += __popc(m & p[k]) - __popc(m & n[k]);
      }
      sp[o*64] = (short)S;
    }
  }
}

// streaming stats over S16: grid 256 blocks x 32 images; 128B-coalesced.
__global__ __launch_bounds__(256) void k_stats2(const short* __restrict__ S16,
        int* __restrict__ part2){
  int tid = threadIdx.x;
  int lane = tid & 63, wid = tid >> 6;
  const short* p = S16 + (size_t)blockIdx.x * 32 * 3200;
  int rs[13], rq[13];
#pragma unroll
  for (int k=0;k<13;k++){ rs[k]=0; rq[k]=0; }
#pragma unroll 1
  for (int im=0; im<32; ++im){
    const short* q = p + im*3200 + tid;
#pragma unroll
    for (int k=0;k<13;k++){
      if (wid + 4*k < 50){
        int v = q[256*k];
        rs[k] += v; rq[k] += v*v;
      }
    }
  }
#pragma unroll
  for (int k=0;k<13;k++){
    int o = wid + 4*k;
    if (o < 50){
      int s = rs[k], q2 = rq[k];
#pragma unroll
      for (int d=32; d>0; d>>=1){ s += __shfl_down(s,d); q2 += __shfl_down(q2,d); }
      if (lane==0){
        part2[blockIdx.x*100 + o*2]     = s;
        part2[blockIdx.x*100 + o*2 + 1] = q2;
      }
    }
  }
}

// one block per channel; sums nchunk partial entries (layout [chunk][100])
__global__ __launch_bounds__(256) void k_reduce2(const int* __restrict__ part2,
        int nchunk, const float* __restrict__ alpha2, const float* __restrict__ g,
        const float* __restrict__ b, float* __restrict__ s2t2){
  __shared__ long long rs[256], rq[256];
  int o = blockIdx.x;          // 0..49
  int tid = threadIdx.x;
  long long s=0, q=0;
  for (int i=tid;i<nchunk;i+=256){
    s += part2[i*100 + o*2];
    q += part2[i*100 + o*2 + 1];
  }
  rs[tid]=s; rq[tid]=q;
  __syncthreads();
  for (int d=128; d>0; d>>=1){
    if (tid<d){ rs[tid]+=rs[tid+d]; rq[tid]+=rq[tid+d]; }
    __syncthreads();
  }
  if (tid==0){
    double N = 8192.0*64.0;
    double meanS = (double)rs[0]/N, E2 = (double)rq[0]/N;
    double varS = E2 - meanS*meanS;
    double a = (double)alpha2[o];
    double mean_g = a*meanS, var_g = a*a*varS;
    double r = 1.0/sqrt(var_g + 1e-5);
    double sc = (double)g[o]*r;
    s2t2[o*2]   = (float)(sc*a);                      // applied to integer S
    s2t2[o*2+1] = (float)((double)b[o] - mean_g*sc);
  }
}

#define BIN2_POOL_BODY                                                        \
    unsigned long long bal = __ballot(cond);                                  \
    unsigned long long t4 = bal | (bal>>1) | (bal>>8) | (bal>>9);             \
    bool pb = (lane < 16) && ((t4 >> (16*(lane>>2) + 2*(lane&3))) & 1ull);    \
    unsigned long long bal2 = __ballot(pb);                                   \
    if (lane==0){                                                             \
      unsigned pooled16 = (unsigned)(bal2 & 0xFFFFull);                       \
      lw[wid*25 + (o>>1)] |= pooled16 << (16*(o&1));                          \
    }

// bin2: read S16, threshold, ballot-pool, pack. 4 img/block, grid 2048.
__global__ __launch_bounds__(256) void k_bin2_lite(const short* __restrict__ S16,
    const float* __restrict__ s2t2, unsigned* __restrict__ mask2){
  __shared__ float st[100];
  __shared__ unsigned lw[100];
  int tid = threadIdx.x;
  if (tid < 100){ st[tid] = s2t2[tid]; lw[tid] = 0u; }
  __syncthreads();
  int lane = tid & 63, wid = tid >> 6;
  size_t img = (size_t)blockIdx.x*4 + wid;
#pragma unroll 1
  for (int o=0;o<50;o++){
    int S = S16[(img*50 + o)*64 + lane];
    bool cond = fmaf((float)S, st[o*2], st[o*2+1]) > 0.f;
    BIN2_POOL_BODY
  }
  __syncthreads();
  if (tid < 100) mask2[blockIdx.x*100 + tid] = lw[tid];
}

// ---------------------------------------------------------------------------
// Stage 3: binary fc1 (800 -> 500). 8 img/block, grid 1024.
// ---------------------------------------------------------------------------
__global__ __launch_bounds__(256) void k_fc1(const unsigned* __restrict__ mask2,
    const unsigned* __restrict__ wpos, const unsigned* __restrict__ wneg,
    const int* __restrict__ flags3, short* __restrict__ S3){
  __shared__ unsigned m2s[8*25];
  __shared__ short s3s[8*500];
  int tid = threadIdx.x;
  size_t base = (size_t)blockIdx.x * 8;
  for (int i=tid;i<200;i+=256) m2s[i] = mask2[base*25 + i];
  __syncthreads();
  int f = 0;
  for (int i=0;i<49;i++) f |= flags3[i];
  int bl = tid & 7;
  int jg = tid >> 3;
  const unsigned* mrow = &m2s[bl*25];
  if (f == 0){
    int pbase = 0;
#pragma unroll
    for (int w=0;w<25;w++) pbase += __popc(mrow[w]);
#pragma unroll 1
    for (int j=jg; j<500; j+=32){
      const unsigned* n = &wneg[j*25];
      int Sn = 0;
#pragma unroll
      for (int w=0;w<25;w++) Sn += __popc(mrow[w] & n[w]);
      s3s[bl*500 + j] = (short)(pbase - 2*Sn);
    }
  } else {
#pragma unroll 1
    for (int j=jg; j<500; j+=32){
      const unsigned* p = &wpos[j*25];
      const unsigned* n = &wneg[j*25];
      int S = 0;
#pragma unroll
      for (int w=0;w<25;w++){
        unsigned m = mrow[w];
        S += __popc(m & p[w]) - __popc(m & n[w]);
      }
      s3s[bl*500 + j] = (short)S;
    }
  }
  __syncthreads();
  for (int i=tid;i<8*500;i+=256) S3[base*500 + i] = s3s[i];
}

// per-feature batch stats of S3 (int, exact): 64 images/block, 128 blocks
__global__ __launch_bounds__(256) void k_stats3(const short* __restrict__ S3,
                                                int* __restrict__ part3){
  int tid = threadIdx.x;
  const short* p = &S3[(size_t)blockIdx.x * 64 * 500];
  int s0=0,q0=0,s1=0,q1=0;
  for (int b=0;b<64;b++){
    int v0 = p[b*500 + tid];
    s0 += v0; q0 += v0*v0;
    if (tid < 244){
      int v1 = p[b*500 + tid + 256];
      s1 += v1; q1 += v1*v1;
    }
  }
  part3[blockIdx.x*1000 + tid*2]     = s0;
  part3[blockIdx.x*1000 + tid*2 + 1] = q0;
  if (tid < 244){
    part3[blockIdx.x*1000 + (tid+256)*2]     = s1;
    part3[blockIdx.x*1000 + (tid+256)*2 + 1] = q1;
  }
}

// one block per feature j; sums nchunk partials
__global__ __launch_bounds__(256) void k_reduce3(const int* __restrict__ part3,
        int nchunk, const float* __restrict__ alpha3, const float* __restrict__ g,
        const float* __restrict__ b, float* __restrict__ s3t3){
  __shared__ long long rs[256], rq[256];
  int j = blockIdx.x;          // 0..499
  int tid = threadIdx.x;
  long long s=0, q=0;
  for (int i=tid;i<nchunk;i+=256){
    s += part3[i*1000 + j*2];
    q += part3[i*1000 + j*2 + 1];
  }
  rs[tid]=s; rq[tid]=q;
  __syncthreads();
  for (int d=128; d>0; d>>=1){
    if (tid<d){ rs[tid]+=rs[tid+d]; rq[tid]+=rq[tid+d]; }
    __syncthreads();
  }
  if (tid==0){
    double N = 8192.0;
    double meanS = (double)rs[0]/N, E2 = (double)rq[0]/N;
    double varS = E2 - meanS*meanS;
    double a = (double)alpha3[j];
    double mean_u = a*meanS, var_u = a*a*varS;
    double r = 1.0/sqrt(var_u + 1e-5);
    double sc = (double)g[j]*r;
    s3t3[j*2]   = (float)(sc*a);
    s3t3[j*2+1] = (float)((double)b[j] - mean_u*sc);
  }
}

// h3 = relu(s3*S3 + t3); out = h3 @ fc2_w^T + fc2_b
__global__ __launch_bounds__(256) void k_final(const short* __restrict__ S3,
    const float* __restrict__ s3t3, const float* __restrict__ fc2w,
    const float* __restrict__ fc2b, float* __restrict__ out){
  __shared__ float w[5000];
  __shared__ float st[1000];
  __shared__ float bias[10];
  int tid = threadIdx.x;
  for (int i=tid;i<5000;i+=256) w[i] = fc2w[i];
  for (int i=tid;i<1000;i+=256) st[i] = s3t3[i];
  if (tid<10) bias[tid] = fc2b[tid];
  __syncthreads();
  int sub = tid & 7;
  int li  = tid >> 3;
  size_t b = (size_t)blockIdx.x*32 + li;
  const short* sp = &S3[b*500];
  float acc[10];
#pragma unroll
  for (int m=0;m<10;m++) acc[m] = 0.f;
#pragma unroll 1
  for (int j=sub; j<500; j+=8){
    float h = fmaf((float)sp[j], st[j*2], st[j*2+1]);
    h = fmaxf(h, 0.f);
#pragma unroll
    for (int m=0;m<10;m++) acc[m] = fmaf(h, w[m*500+j], acc[m]);
  }
#pragma unroll
  for (int m=0;m<10;m++){
    float v = acc[m];
    v += __shfl_xor(v, 1);
    v += __shfl_xor(v, 2);
    v += __shfl_xor(v, 4);
    acc[m] = v;
  }
  if (sub == 0){
#pragma unroll
    for (int m=0;m<10;m++) out[b*10 + m] = acc[m] + bias[m];
  }
}

// ---------------------------------------------------------------------------
extern "C" void kernel_launch(void* const* d_in, const int* in_sizes, int n_in,
                              void* d_out, int out_size, void* d_ws, size_t ws_size,
                              hipStream_t stream){
  const float* x    = (const float*)d_in[0];
  const float* w1   = (const float*)d_in[1];
  const float* bn1g = (const float*)d_in[2];
  const float* bn1b = (const float*)d_in[3];
  const float* w2   = (const float*)d_in[4];
  const float* bn2g = (const float*)d_in[5];
  const float* bn2b = (const float*)d_in[6];
  const float* w3   = (const float*)d_in[7];
  const float* bn3g = (const float*)d_in[8];
  const float* bn3b = (const float*)d_in[9];
  const float* w4   = (const float*)d_in[10];
  const float* b4   = (const float*)d_in[11];
  float* out = (float*)d_out;
  (void)in_sizes; (void)n_in; (void)out_size;

  char* wsb = (char*)d_ws;
  size_t off = 0;
  auto alloc = [&](size_t n){ size_t o = off; off = (off + n + 255) & ~(size_t)255; return o; };
  float*    s1t1   = (float*)(wsb + alloc(40*sizeof(float)));
  float*    s2t2   = (float*)(wsb + alloc(100*sizeof(float)));
  float*    s3t3   = (float*)(wsb + alloc(1000*sizeof(float)));
  float*    alpha2 = (float*)(wsb + alloc(50*sizeof(float)));
  float*    alpha3 = (float*)(wsb + alloc(500*sizeof(float)));
  int*      flags2 = (int*)(wsb + alloc(5*4));
  int*      flags3 = (int*)(wsb + alloc(49*4));
  unsigned* wpos2  = (unsigned*)(wsb + alloc(1250*4));
  unsigned* wneg2  = (unsigned*)(wsb + alloc(1250*4));
  unsigned* wpos3  = (unsigned*)(wsb + alloc(12500*4));
  unsigned* wneg3  = (unsigned*)(wsb + alloc(12500*4));
  float*    part1  = (float*)(wsb + alloc(1024*40*4));
  int*      part2  = (int*)(wsb + alloc(2048*100*4));
  int*      part3  = (int*)(wsb + alloc(128*1000*4));
  unsigned* mask1  = (unsigned*)(wsb + alloc((size_t)BATCH*144*4));
  unsigned* mask2  = (unsigned*)(wsb + alloc((size_t)BATCH*25*4));
  short*    S3     = (short*)(wsb + alloc((size_t)BATCH*500*2));
  // optional staging buffers (runtime-gated on ws_size)
  short*    S16    = (short*)(wsb + alloc((size_t)BATCH*50*64*2));
  bool useS16 = (ws_size >= off);
  float2*   c1ext  = (float2*)(wsb + alloc((size_t)10*NJOB*8));
  bool useMM  = (ws_size >= off);

  hipLaunchKernelGGL(k_pack, dim3(54), dim3(256), 0, stream,
                     w2, w3, wpos2, wneg2, alpha2, wpos3, wneg3, alpha3, flags2, flags3);
  if (useMM)
    hipLaunchKernelGGL(HIP_KERNEL_NAME(k_conv1_stats<true>),  dim3(1024), dim3(256), 0, stream, x, w1, bn1g, part1, c1ext);
  else
    hipLaunchKernelGGL(HIP_KERNEL_NAME(k_conv1_stats<false>), dim3(1024), dim3(256), 0, stream, x, w1, bn1g, part1, c1ext);
  hipLaunchKernelGGL(k_reduce1,      dim3(20),    dim3(256), 0, stream, part1, bn1g, bn1b, s1t1);

  if (useMM && useS16){
    hipLaunchKernelGGL(k_conv2f,     dim3(2048),  dim3(256), 0, stream, c1ext, s1t1, wpos2, wneg2, flags2, S16);
  } else {
    hipLaunchKernelGGL(k_conv1_bin,  dim3(1024),  dim3(256), 0, stream, x, w1, s1t1, mask1);
    hipLaunchKernelGGL(k_conv2,      dim3(2048),  dim3(256), 0, stream, mask1, wpos2, wneg2, flags2, S16);
  }
  hipLaunchKernelGGL(k_stats2,       dim3(256),   dim3(256), 0, stream, S16, part2);
  hipLaunchKernelGGL(k_reduce2,      dim3(50),    dim3(256), 0, stream, part2, 256, alpha2, bn2g, bn2b, s2t2);
  hipLaunchKernelGGL(k_bin2_lite,    dim3(2048),  dim3(256), 0, stream, S16, s2t2, mask2);
  hipLaunchKernelGGL(k_fc1,          dim3(1024),  dim3(256), 0, stream, mask2, wpos3, wneg3, flags3, S3);
  hipLaunchKernelGGL(k_stats3,       dim3(128),   dim3(256), 0, stream, S3, part3);
  hipLaunchKernelGGL(k_reduce3,      dim3(500),   dim3(256), 0, stream, part3, 128, alpha3, bn3g, bn3b, s3t3);
  hipLaunchKernelGGL(k_final,        dim3(256),   dim3(256), 0, stream, S3, s3t3, w4, b4, out);
}

// Round 18
// 306.398 us; speedup vs baseline: 1.1957x; 1.0096x over previous
//
#include <hip/hip_runtime.h>
#include <stdint.h>

#define BATCH 8192
#define NJOB  1179648   // 8192*144

// ---------------------------------------------------------------------------
// Stage 0 (merged): pack binarized weights + alphas + per-block zero flags.
// ---------------------------------------------------------------------------
__global__ __launch_bounds__(256) void k_pack(const float* __restrict__ w2,
    const float* __restrict__ w3, unsigned* __restrict__ wpos2,
    unsigned* __restrict__ wneg2, float* __restrict__ alpha2,
    unsigned* __restrict__ wpos3, unsigned* __restrict__ wneg3,
    float* __restrict__ alpha3, int* __restrict__ flags2, int* __restrict__ flags3){
  __shared__ int zf;
  int tid = threadIdx.x;
  if (tid == 0) zf = 0;
  __syncthreads();
  if (blockIdx.x < 5){
    int t = blockIdx.x*256 + tid;
    int had0 = 0;
    if (t < 1250){                     // t = o*25 + k
      int o = t/25, k = t%25;
      unsigned p=0, n=0;
      for (int i=0;i<20;i++){
        float v = w2[(o*20+i)*25 + k];
        if (v > 0.f) p |= 1u<<i;
        else if (v < 0.f) n |= 1u<<i;
        else had0 = 1;
      }
      wpos2[t] = p; wneg2[t] = n;
    }
    if (t < 50){
      float s = 0.f;
      for (int i=0;i<500;i++) s += fabsf(w2[t*500+i]);
      alpha2[t] = s / 500.f;
    }
    if (had0) atomicOr(&zf, 1);
    __syncthreads();
    if (tid == 0) flags2[blockIdx.x] = zf;
  } else {
    int t = (blockIdx.x-5)*256 + tid;
    int had0 = 0;
    if (t < 12500){                    // t = j*25 + w
      int j = t/25, w = t%25;
      unsigned p=0, n=0;
      for (int bb=0;bb<32;bb++){
        float v = w3[j*800 + w*32 + bb];
        if (v > 0.f) p |= 1u<<bb;
        else if (v < 0.f) n |= 1u<<bb;
        else had0 = 1;
      }
      wpos3[t] = p; wneg3[t] = n;
    }
    if (t < 500){
      float s = 0.f;
      for (int i=0;i<800;i++) s += fabsf(w3[t*800+i]);
      alpha3[t] = s / 800.f;
    }
    if (had0) atomicOr(&zf, 1);
    __syncthreads();
    if (tid == 0) flags3[blockIdx.x-5] = zf;
  }
}

// ---------------------------------------------------------------------------
// Stage 1: conv1 (fp32). 8 images/block, grid 1024. FOUR channels per outer
// iteration (5 iters) -> patch LDS re-reads halved vs channel-pair form.
// Weights read from global with wave-uniform addresses (scalar path).
// ---------------------------------------------------------------------------

#define CONV1_ROWS4(IPTR)                                                     \
  float vA0=0.f,vA1=0.f,vA2=0.f,vA3=0.f;                                      \
  float vB0=0.f,vB1=0.f,vB2=0.f,vB3=0.f;                                      \
  float vC0=0.f,vC1=0.f,vC2=0.f,vC3=0.f;                                      \
  float vD0=0.f,vD1=0.f,vD2=0.f,vD3=0.f;                                      \
  _Pragma("unroll")                                                           \
  for (int r=0;r<6;r++){                                                      \
    const float2* rp = (const float2*)((IPTR) + r*28);                        \
    float2 p0 = rp[0], p1 = rp[1], p2 = rp[2];                                \
    float row0=p0.x, row1=p0.y, row2=p1.x, row3=p1.y, row4=p2.x, row5=p2.y;   \
    if (r<5){                                                                 \
      _Pragma("unroll")                                                       \
      for (int kx=0;kx<5;kx++){                                               \
        float e0 = (kx==0?row0:kx==1?row1:kx==2?row2:kx==3?row3:row4);        \
        float e1 = (kx==0?row1:kx==1?row2:kx==2?row3:kx==3?row4:row5);        \
        float w = wa[r*5+kx], u = wb[r*5+kx];                                 \
        float c = wc[r*5+kx], d = wd[r*5+kx];                                 \
        vA0=fmaf(e0,w,vA0); vA1=fmaf(e1,w,vA1);                               \
        vB0=fmaf(e0,u,vB0); vB1=fmaf(e1,u,vB1);                               \
        vC0=fmaf(e0,c,vC0); vC1=fmaf(e1,c,vC1);                               \
        vD0=fmaf(e0,d,vD0); vD1=fmaf(e1,d,vD1);                               \
      }                                                                       \
    }                                                                         \
    if (r>0){                                                                 \
      _Pragma("unroll")                                                       \
      for (int kx=0;kx<5;kx++){                                               \
        float e0 = (kx==0?row0:kx==1?row1:kx==2?row2:kx==3?row3:row4);        \
        float e1 = (kx==0?row1:kx==1?row2:kx==2?row3:kx==3?row4:row5);        \
        float w = wa[(r-1)*5+kx], u = wb[(r-1)*5+kx];                         \
        float c = wc[(r-1)*5+kx], d = wd[(r-1)*5+kx];                         \
        vA2=fmaf(e0,w,vA2); vA3=fmaf(e1,w,vA3);                               \
        vB2=fmaf(e0,u,vB2); vB3=fmaf(e1,u,vB3);                               \
        vC2=fmaf(e0,c,vC2); vC3=fmaf(e1,c,vC3);                               \
        vD2=fmaf(e0,d,vD2); vD3=fmaf(e1,d,vD3);                               \
      }                                                                       \
    }                                                                         \
  }

// legacy 2-channel row-streaming (fallback kernel only)
#define CONV1_ROWS(IPTR)                                                      \
  float vA0=0.f,vA1=0.f,vA2=0.f,vA3=0.f;                                      \
  float vB0=0.f,vB1=0.f,vB2=0.f,vB3=0.f;                                      \
  _Pragma("unroll")                                                           \
  for (int r=0;r<6;r++){                                                      \
    const float2* rp = (const float2*)((IPTR) + r*28);                        \
    float2 p0 = rp[0], p1 = rp[1], p2 = rp[2];                                \
    float row0=p0.x, row1=p0.y, row2=p1.x, row3=p1.y, row4=p2.x, row5=p2.y;   \
    if (r<5){                                                                 \
      _Pragma("unroll")                                                       \
      for (int kx=0;kx<5;kx++){                                               \
        float e0 = (kx==0?row0:kx==1?row1:kx==2?row2:kx==3?row3:row4);        \
        float e1 = (kx==0?row1:kx==1?row2:kx==2?row3:kx==3?row4:row5);        \
        float w = wa[r*5+kx], u = wb[r*5+kx];                                 \
        vA0=fmaf(e0,w,vA0); vA1=fmaf(e1,w,vA1);                               \
        vB0=fmaf(e0,u,vB0); vB1=fmaf(e1,u,vB1);                               \
      }                                                                       \
    }                                                                         \
    if (r>0){                                                                 \
      _Pragma("unroll")                                                       \
      for (int kx=0;kx<5;kx++){                                               \
        float e0 = (kx==0?row0:kx==1?row1:kx==2?row2:kx==3?row3:row4);        \
        float e1 = (kx==0?row1:kx==1?row2:kx==2?row3:kx==3?row4:row5);        \
        float w = wa[(r-1)*5+kx], u = wb[(r-1)*5+kx];                         \
        vA2=fmaf(e0,w,vA2); vA3=fmaf(e1,w,vA3);                               \
        vB2=fmaf(e0,u,vB2); vB3=fmaf(e1,u,vB3);                               \
      }                                                                       \
    }                                                                         \
  }

template<bool STORE_MM>
__global__ __launch_bounds__(256) void k_conv1_stats(const float* __restrict__ x,
        const float* __restrict__ w1, const float* __restrict__ g1,
        float* __restrict__ part1, float2* __restrict__ c1ext){
  __shared__ float img[8*784];
  __shared__ float red[4][40];
  int tid = threadIdx.x;
  size_t base = (size_t)blockIdx.x * 8;
  const float4* xv = (const float4*)(x + base*784);
  float4* iv = (float4*)img;
  for (int i=tid;i<1568;i+=256) iv[i] = xv[i];
  __syncthreads();
  int lane = tid & 63, wid = tid >> 6;
#pragma unroll 1
  for (int cq=0; cq<5; ++cq){
    float wa[25], wb[25], wc[25], wd[25];
#pragma unroll
    for (int k=0;k<25;k++){
      wa[k]=w1[(4*cq+0)*25+k]; wb[k]=w1[(4*cq+1)*25+k];
      wc[k]=w1[(4*cq+2)*25+k]; wd[k]=w1[(4*cq+3)*25+k];
    }
    float gA = g1[4*cq+0], gB = g1[4*cq+1], gC = g1[4*cq+2], gD = g1[4*cq+3];
    float sa=0.f, qa=0.f, sb=0.f, qb=0.f;
    float sc2=0.f, qc=0.f, sd=0.f, qd=0.f;
#pragma unroll 1
    for (int job=tid; job<8*144; job+=256){
      int li = job/144, pp = job%144;
      int py = pp/12, px = pp%12;
      const float* ip = &img[li*784 + py*56 + px*2];
      CONV1_ROWS4(ip)
      sa += (vA0+vA1)+(vA2+vA3);
      qa = fmaf(vA0,vA0, fmaf(vA1,vA1, fmaf(vA2,vA2, fmaf(vA3,vA3, qa))));
      sb += (vB0+vB1)+(vB2+vB3);
      qb = fmaf(vB0,vB0, fmaf(vB1,vB1, fmaf(vB2,vB2, fmaf(vB3,vB3, qb))));
      sc2 += (vC0+vC1)+(vC2+vC3);
      qc = fmaf(vC0,vC0, fmaf(vC1,vC1, fmaf(vC2,vC2, fmaf(vC3,vC3, qc))));
      sd += (vD0+vD1)+(vD2+vD3);
      qd = fmaf(vD0,vD0, fmaf(vD1,vD1, fmaf(vD2,vD2, fmaf(vD3,vD3, qd))));
      if (STORE_MM){
        float mxA = fmaxf(fmaxf(vA0,vA1),fmaxf(vA2,vA3));
        float mnA = fminf(fminf(vA0,vA1),fminf(vA2,vA3));
        float mxB = fmaxf(fmaxf(vB0,vB1),fmaxf(vB2,vB3));
        float mnB = fminf(fminf(vB0,vB1),fminf(vB2,vB3));
        float mxC = fmaxf(fmaxf(vC0,vC1),fmaxf(vC2,vC3));
        float mnC = fminf(fminf(vC0,vC1),fminf(vC2,vC3));
        float mxD = fmaxf(fmaxf(vD0,vD1),fmaxf(vD2,vD3));
        float mnD = fminf(fminf(vD0,vD1),fminf(vD2,vD3));
        float eA = (gA > 0.f) ? mxA : mnA;
        float eB = (gB > 0.f) ? mxB : mnB;
        float eC = (gC > 0.f) ? mxC : mnC;
        float eD = (gD > 0.f) ? mxD : mnD;
        size_t J = (base+li)*144 + pp;
        c1ext[(size_t)(2*cq)*NJOB   + J] = make_float2(eA,eB);
        c1ext[(size_t)(2*cq+1)*NJOB + J] = make_float2(eC,eD);
      }
    }
#pragma unroll
    for (int d=32; d>0; d>>=1){
      sa += __shfl_down(sa,d); qa += __shfl_down(qa,d);
      sb += __shfl_down(sb,d); qb += __shfl_down(qb,d);
      sc2 += __shfl_down(sc2,d); qc += __shfl_down(qc,d);
      sd += __shfl_down(sd,d); qd += __shfl_down(qd,d);
    }
    if (lane==0){
      red[wid][(4*cq+0)*2] = sa;  red[wid][(4*cq+0)*2+1] = qa;
      red[wid][(4*cq+1)*2] = sb;  red[wid][(4*cq+1)*2+1] = qb;
      red[wid][(4*cq+2)*2] = sc2; red[wid][(4*cq+2)*2+1] = qc;
      red[wid][(4*cq+3)*2] = sd;  red[wid][(4*cq+3)*2+1] = qd;
    }
  }
  __syncthreads();
  if (tid < 40)
    part1[blockIdx.x*40 + tid] = red[0][tid]+red[1][tid]+red[2][tid]+red[3][tid];
}

// one block per channel; 256 threads; deterministic fixed-pairing tree
__global__ __launch_bounds__(256) void k_reduce1(const float* __restrict__ part1,
        const float* __restrict__ g, const float* __restrict__ b,
        float* __restrict__ s1t1){
  __shared__ double rs[256], rq[256];
  int c = blockIdx.x;          // 0..19
  int tid = threadIdx.x;
  double s=0.0, q=0.0;
  for (int i=tid;i<1024;i+=256){
    s += (double)part1[i*40 + c*2];
    q += (double)part1[i*40 + c*2 + 1];
  }
  rs[tid]=s; rq[tid]=q;
  __syncthreads();
  for (int d=128; d>0; d>>=1){
    if (tid<d){ rs[tid]+=rs[tid+d]; rq[tid]+=rq[tid+d]; }
    __syncthreads();
  }
  if (tid==0){
    double N = 8192.0*576.0;
    double mean = rs[0]/N, var = rq[0]/N - mean*mean;
    double r = 1.0/sqrt(var + 1e-5);
    double sc = (double)g[c]*r;
    s1t1[c*2]   = (float)sc;
    s1t1[c*2+1] = (float)((double)b[c] - mean*sc);
  }
}

// fallback pass B (recompute): conv1 + threshold + OR-pool, per-job LDS word
__global__ __launch_bounds__(256) void k_conv1_bin(const float* __restrict__ x,
        const float* __restrict__ w1, const float* __restrict__ s1t1,
        unsigned* __restrict__ mask1){
  __shared__ float img[8*784];
  __shared__ float st[40];
  __shared__ unsigned lw[8*144];
  int tid = threadIdx.x;
  size_t base = (size_t)blockIdx.x * 8;
  const float4* xv = (const float4*)(x + base*784);
  float4* iv = (float4*)img;
  for (int i=tid;i<1568;i+=256) iv[i] = xv[i];
  for (int i=tid;i<8*144;i+=256) lw[i] = 0u;
  if (tid < 40) st[tid] = s1t1[tid];
  __syncthreads();
#pragma unroll 1
  for (int cg=0; cg<10; ++cg){
    float wa[25], wb[25];
#pragma unroll
    for (int k=0;k<25;k++){ wa[k]=w1[(2*cg)*25+k]; wb[k]=w1[(2*cg+1)*25+k]; }
    float sA = st[(2*cg)*2],   tA = st[(2*cg)*2+1];
    float sB = st[(2*cg+1)*2], tB = st[(2*cg+1)*2+1];
#pragma unroll 1
    for (int job=tid; job<8*144; job+=256){
      int li = job/144, pp = job%144;
      int py = pp/12, px = pp%12;
      const float* ip = &img[li*784 + py*56 + px*2];
      CONV1_ROWS(ip)
      unsigned bA = (fmaf(vA0,sA,tA) > 0.f) || (fmaf(vA1,sA,tA) > 0.f) ||
                    (fmaf(vA2,sA,tA) > 0.f) || (fmaf(vA3,sA,tA) > 0.f);
      unsigned bB = (fmaf(vB0,sB,tB) > 0.f) || (fmaf(vB1,sB,tB) > 0.f) ||
                    (fmaf(vB2,sB,tB) > 0.f) || (fmaf(vB3,sB,tB) > 0.f);
      lw[job] |= (bA << (2*cg)) | (bB << (2*cg+1));
    }
  }
  __syncthreads();
  for (int i=tid;i<8*144;i+=256){
    int li = i/144, pp = i%144;
    mask1[(base+li)*144 + pp] = lw[i];
  }
}

// ---------------------------------------------------------------------------
// Stage 2 FUSED: mask1 computed in-block from c1ext, then popcount -> S16.
// Weight words read directly from global (wave-uniform -> scalar path).
// ---------------------------------------------------------------------------
__global__ __launch_bounds__(256) void k_conv2f(const float2* __restrict__ c1ext,
    const float* __restrict__ s1t1, const unsigned* __restrict__ wpos,
    const unsigned* __restrict__ wneg, const int* __restrict__ flags2,
    short* __restrict__ S16){
  __shared__ unsigned m1[4*144];
  __shared__ float st[40];
  int tid = threadIdx.x;
  size_t base = (size_t)blockIdx.x * 4;
  bool slow = (flags2[0]|flags2[1]|flags2[2]|flags2[3]|flags2[4]) != 0;
  if (tid < 40) st[tid] = s1t1[tid];
  __syncthreads();
  // phase A: binarize conv1 output (threshold on stored extreme)
  for (int job=tid; job<4*144; job+=256){
    int li = job/144, pp = job%144;
    unsigned word = 0;
#pragma unroll
    for (int cg=0; cg<10; ++cg){
      float2 v = c1ext[(size_t)cg*NJOB + (base+li)*144 + pp];
      word |= ((fmaf(v.x, st[4*cg+0], st[4*cg+1]) > 0.f) ? 1u : 0u) << (2*cg);
      word |= ((fmaf(v.y, st[4*cg+2], st[4*cg+3]) > 0.f) ? 1u : 0u) << (2*cg+1);
    }
    m1[job] = word;
  }
  __syncthreads();
  // phase B: binary conv2 popcount (weights via uniform global reads)
  int lane = tid & 63, wid = tid >> 6;
  int y2 = lane >> 3, x2 = lane & 7;
  unsigned mw[25];
  const unsigned* mrow = &m1[wid*144];
#pragma unroll
  for (int ky=0;ky<5;ky++)
#pragma unroll
    for (int kx=0;kx<5;kx++)
      mw[ky*5+kx] = mrow[(y2+ky)*12 + x2+kx];
  short* sp = &S16[((base+wid)*50)*64 + lane];
  if (!slow){
    int pbase = 0;
#pragma unroll
    for (int k=0;k<25;k++) pbase += __popc(mw[k]);
#pragma unroll 1
    for (int o=0;o<50;o++){
      const unsigned* n = &wneg[o*25];
      int Sn=0;
#pragma unroll
      for (int k=0;k<25;k++) Sn += __popc(mw[k] & n[k]);
      sp[o*64] = (short)(pbase - 2*Sn);
    }
  } else {
#pragma unroll 1
    for (int o=0;o<50;o++){
      const unsigned* p = &wpos[o*25];
      const unsigned* n = &wneg[o*25];
      int S=0;
#pragma unroll
      for (int k=0;k<25;k++){
        unsigned m = mw[k];
        S += __popc(m & p[k]) - __popc(m & n[k]);
      }
      sp[o*64] = (short)S;
    }
  }
}

// legacy conv2 from mask1 (fallback when !useMM): S16 only
__global__ __launch_bounds__(256) void k_conv2(const unsigned* __restrict__ mask1,
    const unsigned* __restrict__ wpos, const unsigned* __restrict__ wneg,
    const int* __restrict__ flags2, short* __restrict__ S16){
  __shared__ unsigned m1[4*144];
  int tid = threadIdx.x;
  size_t base = (size_t)blockIdx.x * 4;
  bool slow = (flags2[0]|flags2[1]|flags2[2]|flags2[3]|flags2[4]) != 0;
  for (int i=tid;i<4*144;i+=256) m1[i] = mask1[base*144 + i];
  __syncthreads();
  int lane = tid & 63, wid = tid >> 6;
  int y2 = lane >> 3, x2 = lane & 7;
  unsigned mw[25];
  const unsigned* mrow = &m1[wid*144];
#pragma unroll
  for (int ky=0;ky<5;ky++)
#pragma unroll
    for (int kx=0;kx<5;kx++)
      mw[ky*5+kx] = mrow[(y2+ky)*12 + x2+kx];
  short* sp = &S16[((base+wid)*50)*64 + lane];
  if (!slow){
    int pbase = 0;
#pragma unroll
    for (int k=0;k<25;k++) pbase += __popc(mw[k]);
#pragma unroll 1
    for (int o=0;o<50;o++){
      const unsigned* n = &wneg[o*25];
      int Sn=0;
#pragma unroll
      for (int k=0;k<25;k++) Sn += __popc(mw[k] & n[k]);
      sp[o*64] = (short)(pbase - 2*Sn);
    }
  } else {
#pragma unroll 1
    for (int o=0;o<50;o++){
      const unsigned* p = &wpos[o*25];
      const unsigned* n = &wneg[o*25];
      int S=0;
#pragma unroll
      for (int k=0;k<25;k++){
        unsigned m = mw[k];
        S += __popc(m & p[k]) - __popc(m & n[k]);
      }
      sp[o*64] = (short)S;
    }
  }
}

// streaming stats over S16: grid 256 blocks x 32 images; 128B-coalesced.
__global__ __launch_bounds__(256) void k_stats2(const short* __restrict__ S16,
        int* __restrict__ part2){
  int tid = threadIdx.x;
  int lane = tid & 63, wid = tid >> 6;
  const short* p = S16 + (size_t)blockIdx.x * 32 * 3200;
  int rs[13], rq[13];
#pragma unroll
  for (int k=0;k<13;k++){ rs[k]=0; rq[k]=0; }
#pragma unroll 1
  for (int im=0; im<32; ++im){
    const short* q = p + im*3200 + tid;
#pragma unroll
    for (int k=0;k<13;k++){
      if (wid + 4*k < 50){
        int v = q[256*k];
        rs[k] += v; rq[k] += v*v;
      }
    }
  }
#pragma unroll
  for (int k=0;k<13;k++){
    int o = wid + 4*k;
    if (o < 50){
      int s = rs[k], q2 = rq[k];
#pragma unroll
      for (int d=32; d>0; d>>=1){ s += __shfl_down(s,d); q2 += __shfl_down(q2,d); }
      if (lane==0){
        part2[blockIdx.x*100 + o*2]     = s;
        part2[blockIdx.x*100 + o*2 + 1] = q2;
      }
    }
  }
}

// one block per channel; sums nchunk partial entries (layout [chunk][100])
__global__ __launch_bounds__(256) void k_reduce2(const int* __restrict__ part2,
        int nchunk, const float* __restrict__ alpha2, const float* __restrict__ g,
        const float* __restrict__ b, float* __restrict__ s2t2){
  __shared__ long long rs[256], rq[256];
  int o = blockIdx.x;          // 0..49
  int tid = threadIdx.x;
  long long s=0, q=0;
  for (int i=tid;i<nchunk;i+=256){
    s += part2[i*100 + o*2];
    q += part2[i*100 + o*2 + 1];
  }
  rs[tid]=s; rq[tid]=q;
  __syncthreads();
  for (int d=128; d>0; d>>=1){
    if (tid<d){ rs[tid]+=rs[tid+d]; rq[tid]+=rq[tid+d]; }
    __syncthreads();
  }
  if (tid==0){
    double N = 8192.0*64.0;
    double meanS = (double)rs[0]/N, E2 = (double)rq[0]/N;
    double varS = E2 - meanS*meanS;
    double a = (double)alpha2[o];
    double mean_g = a*meanS, var_g = a*a*varS;
    double r = 1.0/sqrt(var_g + 1e-5);
    double sc = (double)g[o]*r;
    s2t2[o*2]   = (float)(sc*a);                      // applied to integer S
    s2t2[o*2+1] = (float)((double)b[o] - mean_g*sc);
  }
}

#define BIN2_POOL_BODY                                                        \
    unsigned long long bal = __ballot(cond);                                  \
    unsigned long long t4 = bal | (bal>>1) | (bal>>8) | (bal>>9);             \
    bool pb = (lane < 16) && ((t4 >> (16*(lane>>2) + 2*(lane&3))) & 1ull);    \
    unsigned long long bal2 = __ballot(pb);                                   \
    if (lane==0){                                                             \
      unsigned pooled16 = (unsigned)(bal2 & 0xFFFFull);                       \
      lw[wid*25 + (o>>1)] |= pooled16 << (16*(o&1));                          \
    }

// bin2: read S16, threshold, ballot-pool, pack. 4 img/block, grid 2048.
__global__ __launch_bounds__(256) void k_bin2_lite(const short* __restrict__ S16,
    const float* __restrict__ s2t2, unsigned* __restrict__ mask2){
  __shared__ float st[100];
  __shared__ unsigned lw[100];
  int tid = threadIdx.x;
  if (tid < 100){ st[tid] = s2t2[tid]; lw[tid] = 0u; }
  __syncthreads();
  int lane = tid & 63, wid = tid >> 6;
  size_t img = (size_t)blockIdx.x*4 + wid;
#pragma unroll 1
  for (int o=0;o<50;o++){
    int S = S16[(img*50 + o)*64 + lane];
    bool cond = fmaf((float)S, st[o*2], st[o*2+1]) > 0.f;
    BIN2_POOL_BODY
  }
  __syncthreads();
  if (tid < 100) mask2[blockIdx.x*100 + tid] = lw[tid];
}

// ---------------------------------------------------------------------------
// Stage 3: binary fc1 (800 -> 500). 8 img/block, grid 1024.
// ---------------------------------------------------------------------------
__global__ __launch_bounds__(256) void k_fc1(const unsigned* __restrict__ mask2,
    const unsigned* __restrict__ wpos, const unsigned* __restrict__ wneg,
    const int* __restrict__ flags3, short* __restrict__ S3){
  __shared__ unsigned m2s[8*25];
  __shared__ short s3s[8*500];
  int tid = threadIdx.x;
  size_t base = (size_t)blockIdx.x * 8;
  for (int i=tid;i<200;i+=256) m2s[i] = mask2[base*25 + i];
  __syncthreads();
  int f = 0;
  for (int i=0;i<49;i++) f |= flags3[i];
  int bl = tid & 7;
  int jg = tid >> 3;
  const unsigned* mrow = &m2s[bl*25];
  if (f == 0){
    int pbase = 0;
#pragma unroll
    for (int w=0;w<25;w++) pbase += __popc(mrow[w]);
#pragma unroll 1
    for (int j=jg; j<500; j+=32){
      const unsigned* n = &wneg[j*25];
      int Sn = 0;
#pragma unroll
      for (int w=0;w<25;w++) Sn += __popc(mrow[w] & n[w]);
      s3s[bl*500 + j] = (short)(pbase - 2*Sn);
    }
  } else {
#pragma unroll 1
    for (int j=jg; j<500; j+=32){
      const unsigned* p = &wpos[j*25];
      const unsigned* n = &wneg[j*25];
      int S = 0;
#pragma unroll
      for (int w=0;w<25;w++){
        unsigned m = mrow[w];
        S += __popc(m & p[w]) - __popc(m & n[w]);
      }
      s3s[bl*500 + j] = (short)S;
    }
  }
  __syncthreads();
  for (int i=tid;i<8*500;i+=256) S3[base*500 + i] = s3s[i];
}

// per-feature batch stats of S3 (int, exact): 64 images/block, 128 blocks
__global__ __launch_bounds__(256) void k_stats3(const short* __restrict__ S3,
                                                int* __restrict__ part3){
  int tid = threadIdx.x;
  const short* p = &S3[(size_t)blockIdx.x * 64 * 500];
  int s0=0,q0=0,s1=0,q1=0;
  for (int b=0;b<64;b++){
    int v0 = p[b*500 + tid];
    s0 += v0; q0 += v0*v0;
    if (tid < 244){
      int v1 = p[b*500 + tid + 256];
      s1 += v1; q1 += v1*v1;
    }
  }
  part3[blockIdx.x*1000 + tid*2]     = s0;
  part3[blockIdx.x*1000 + tid*2 + 1] = q0;
  if (tid < 244){
    part3[blockIdx.x*1000 + (tid+256)*2]     = s1;
    part3[blockIdx.x*1000 + (tid+256)*2 + 1] = q1;
  }
}

// one block per feature j; sums nchunk partials
__global__ __launch_bounds__(256) void k_reduce3(const int* __restrict__ part3,
        int nchunk, const float* __restrict__ alpha3, const float* __restrict__ g,
        const float* __restrict__ b, float* __restrict__ s3t3){
  __shared__ long long rs[256], rq[256];
  int j = blockIdx.x;          // 0..499
  int tid = threadIdx.x;
  long long s=0, q=0;
  for (int i=tid;i<nchunk;i+=256){
    s += part3[i*1000 + j*2];
    q += part3[i*1000 + j*2 + 1];
  }
  rs[tid]=s; rq[tid]=q;
  __syncthreads();
  for (int d=128; d>0; d>>=1){
    if (tid<d){ rs[tid]+=rs[tid+d]; rq[tid]+=rq[tid+d]; }
    __syncthreads();
  }
  if (tid==0){
    double N = 8192.0;
    double meanS = (double)rs[0]/N, E2 = (double)rq[0]/N;
    double varS = E2 - meanS*meanS;
    double a = (double)alpha3[j];
    double mean_u = a*meanS, var_u = a*a*varS;
    double r = 1.0/sqrt(var_u + 1e-5);
    double sc = (double)g[j]*r;
    s3t3[j*2]   = (float)(sc*a);
    s3t3[j*2+1] = (float)((double)b[j] - mean_u*sc);
  }
}

// h3 = relu(s3*S3 + t3); out = h3 @ fc2_w^T + fc2_b
__global__ __launch_bounds__(256) void k_final(const short* __restrict__ S3,
    const float* __restrict__ s3t3, const float* __restrict__ fc2w,
    const float* __restrict__ fc2b, float* __restrict__ out){
  __shared__ float w[5000];
  __shared__ float st[1000];
  __shared__ float bias[10];
  int tid = threadIdx.x;
  for (int i=tid;i<5000;i+=256) w[i] = fc2w[i];
  for (int i=tid;i<1000;i+=256) st[i] = s3t3[i];
  if (tid<10) bias[tid] = fc2b[tid];
  __syncthreads();
  int sub = tid & 7;
  int li  = tid >> 3;
  size_t b = (size_t)blockIdx.x*32 + li;
  const short* sp = &S3[b*500];
  float acc[10];
#pragma unroll
  for (int m=0;m<10;m++) acc[m] = 0.f;
#pragma unroll 1
  for (int j=sub; j<500; j+=8){
    float h = fmaf((float)sp[j], st[j*2], st[j*2+1]);
    h = fmaxf(h, 0.f);
#pragma unroll
    for (int m=0;m<10;m++) acc[m] = fmaf(h, w[m*500+j], acc[m]);
  }
#pragma unroll
  for (int m=0;m<10;m++){
    float v = acc[m];
    v += __shfl_xor(v, 1);
    v += __shfl_xor(v, 2);
    v += __shfl_xor(v, 4);
    acc[m] = v;
  }
  if (sub == 0){
#pragma unroll
    for (int m=0;m<10;m++) out[b*10 + m] = acc[m] + bias[m];
  }
}

// ---------------------------------------------------------------------------
extern "C" void kernel_launch(void* const* d_in, const int* in_sizes, int n_in,
                              void* d_out, int out_size, void* d_ws, size_t ws_size,
                              hipStream_t stream){
  const float* x    = (const float*)d_in[0];
  const float* w1   = (const float*)d_in[1];
  const float* bn1g = (const float*)d_in[2];
  const float* bn1b = (const float*)d_in[3];
  const float* w2   = (const float*)d_in[4];
  const float* bn2g = (const float*)d_in[5];
  const float* bn2b = (const float*)d_in[6];
  const float* w3   = (const float*)d_in[7];
  const float* bn3g = (const float*)d_in[8];
  const float* bn3b = (const float*)d_in[9];
  const float* w4   = (const float*)d_in[10];
  const float* b4   = (const float*)d_in[11];
  float* out = (float*)d_out;
  (void)in_sizes; (void)n_in; (void)out_size;

  char* wsb = (char*)d_ws;
  size_t off = 0;
  auto alloc = [&](size_t n){ size_t o = off; off = (off + n + 255) & ~(size_t)255; return o; };
  float*    s1t1   = (float*)(wsb + alloc(40*sizeof(float)));
  float*    s2t2   = (float*)(wsb + alloc(100*sizeof(float)));
  float*    s3t3   = (float*)(wsb + alloc(1000*sizeof(float)));
  float*    alpha2 = (float*)(wsb + alloc(50*sizeof(float)));
  float*    alpha3 = (float*)(wsb + alloc(500*sizeof(float)));
  int*      flags2 = (int*)(wsb + alloc(5*4));
  int*      flags3 = (int*)(wsb + alloc(49*4));
  unsigned* wpos2  = (unsigned*)(wsb + alloc(1250*4));
  unsigned* wneg2  = (unsigned*)(wsb + alloc(1250*4));
  unsigned* wpos3  = (unsigned*)(wsb + alloc(12500*4));
  unsigned* wneg3  = (unsigned*)(wsb + alloc(12500*4));
  float*    part1  = (float*)(wsb + alloc(1024*40*4));
  int*      part2  = (int*)(wsb + alloc(2048*100*4));
  int*      part3  = (int*)(wsb + alloc(128*1000*4));
  unsigned* mask1  = (unsigned*)(wsb + alloc((size_t)BATCH*144*4));
  unsigned* mask2  = (unsigned*)(wsb + alloc((size_t)BATCH*25*4));
  short*    S3     = (short*)(wsb + alloc((size_t)BATCH*500*2));
  // optional staging buffers (runtime-gated on ws_size)
  short*    S16    = (short*)(wsb + alloc((size_t)BATCH*50*64*2));
  bool useS16 = (ws_size >= off);
  float2*   c1ext  = (float2*)(wsb + alloc((size_t)10*NJOB*8));
  bool useMM  = (ws_size >= off);

  hipLaunchKernelGGL(k_pack, dim3(54), dim3(256), 0, stream,
                     w2, w3, wpos2, wneg2, alpha2, wpos3, wneg3, alpha3, flags2, flags3);
  if (useMM)
    hipLaunchKernelGGL(HIP_KERNEL_NAME(k_conv1_stats<true>),  dim3(1024), dim3(256), 0, stream, x, w1, bn1g, part1, c1ext);
  else
    hipLaunchKernelGGL(HIP_KERNEL_NAME(k_conv1_stats<false>), dim3(1024), dim3(256), 0, stream, x, w1, bn1g, part1, c1ext);
  hipLaunchKernelGGL(k_reduce1,      dim3(20),    dim3(256), 0, stream, part1, bn1g, bn1b, s1t1);

  if (useMM && useS16){
    hipLaunchKernelGGL(k_conv2f,     dim3(2048),  dim3(256), 0, stream, c1ext, s1t1, wpos2, wneg2, flags2, S16);
  } else {
    hipLaunchKernelGGL(k_conv1_bin,  dim3(1024),  dim3(256), 0, stream, x, w1, s1t1, mask1);
    hipLaunchKernelGGL(k_conv2,      dim3(2048),  dim3(256), 0, stream, mask1, wpos2, wneg2, flags2, S16);
  }
  hipLaunchKernelGGL(k_stats2,       dim3(256),   dim3(256), 0, stream, S16, part2);
  hipLaunchKernelGGL(k_reduce2,      dim3(50),    dim3(256), 0, stream, part2, 256, alpha2, bn2g, bn2b, s2t2);
  hipLaunchKernelGGL(k_bin2_lite,    dim3(2048),  dim3(256), 0, stream, S16, s2t2, mask2);
  hipLaunchKernelGGL(k_fc1,          dim3(1024),  dim3(256), 0, stream, mask2, wpos3, wneg3, flags3, S3);
  hipLaunchKernelGGL(k_stats3,       dim3(128),   dim3(256), 0, stream, S3, part3);
  hipLaunchKernelGGL(k_reduce3,      dim3(500),   dim3(256), 0, stream, part3, 128, alpha3, bn3g, bn3b, s3t3);
  hipLaunchKernelGGL(k_final,        dim3(256),   dim3(256), 0, stream, S3, s3t3, w4, b4, out);
}